// Round 12
// baseline (165.313 us; speedup 1.0000x reference)
//
#include <hip/hip_runtime.h>
#include <math.h>

typedef unsigned short u16;
typedef __bf16 bf16x8 __attribute__((ext_vector_type(8)));
typedef float f32x4 __attribute__((ext_vector_type(4)));

// Problem constants
constexpr int Bc   = 2;
constexpr int Sc   = 4096;
constexpr int HIDc = 768;
constexpr int Hc   = 12;
constexpr int Dc   = 64;
constexpr int Wc   = 128;
constexpr int Mc   = Bc * Sc;

// attention tiling (v5): 128 queries/block, 8 waves, per-wave 18-tile band
constexpr int QT3  = 128;
constexpr int NCT3 = 18;

#define VM_BAR(N) asm volatile("s_waitcnt vmcnt(" #N ")\n\ts_barrier" ::: "memory")
#define BAR()     asm volatile("s_barrier" ::: "memory")

static __device__ __forceinline__ void load_lds16(const void* g, void* l) {
    __builtin_amdgcn_global_load_lds(
        (const __attribute__((address_space(1))) void*)g,
        (__attribute__((address_space(3))) void*)l, 16, 0, 0);
}
static __device__ __forceinline__ u16 to_bf16(float f) {
    return __builtin_bit_cast(u16, (__bf16)f);
}

// ---------------------------------------------------------------------------
// Fused prep: blocks [0,6144): x fp32 -> bf16 (+ zpad fill in block 0);
// blocks [6144,8448): transpose W [K][N] fp32 -> Wt [N][K] bf16.
// ---------------------------------------------------------------------------
__global__ __launch_bounds__(256) void prep_all(
    const float* __restrict__ x, u16* __restrict__ xb, u16* __restrict__ zpad,
    const float* __restrict__ Wq, const float* __restrict__ Wk,
    const float* __restrict__ Wv, const float* __restrict__ Wd,
    u16* __restrict__ wqt, u16* __restrict__ wkt,
    u16* __restrict__ wvt, u16* __restrict__ wdt)
{
    const int bid = blockIdx.x;
    if (bid < 6144) {
        int i = bid * 256 + threadIdx.x;
        float4 v = ((const float4*)x)[i];
        ushort4 o;
        o.x = to_bf16(v.x); o.y = to_bf16(v.y);
        o.z = to_bf16(v.z); o.w = to_bf16(v.w);
        ((ushort4*)xb)[i] = o;
        if (bid == 0 && threadIdx.x < 128)
            ((int4*)zpad)[threadIdx.x] = make_int4(0, 0, 0, 0);  // 2KB zeros
    } else {
        int r = bid - 6144;                 // 0..2303
        int z = r / 576, xy = r - z * 576;  // 576 = 24*24 tiles per matrix
        const float* W = z == 0 ? Wq : z == 1 ? Wk : z == 2 ? Wv : Wd;
        u16* T         = z == 0 ? wqt : z == 1 ? wkt : z == 2 ? wvt : wdt;
        __shared__ float t[32][33];
        const int bx = (xy % 24) * 32, by = (xy / 24) * 32;
        const int tx = threadIdx.x & 31, ty = threadIdx.x >> 5;
#pragma unroll
        for (int i = 0; i < 32; i += 8)
            t[ty + i][tx] = W[(size_t)(by + ty + i) * HIDc + bx + tx];
        __syncthreads();
#pragma unroll
        for (int i = 0; i < 32; i += 8)
            T[(size_t)(bx + ty + i) * HIDc + by + tx] = to_bf16(t[tx][ty + i]);
    }
}

// ---------------------------------------------------------------------------
// A-only BK=64 stager: 128 rows x 64 k = 16KB/buffer; 4 loads/thread.
// Row = 128B = 8 x 16B slots; swizzle slot8 = phys ^ (row&7).
// ---------------------------------------------------------------------------
__device__ __forceinline__ void stageA64(const u16* __restrict__ A,
                                         int m0, int k0, u16* lds)
{
    const int tid = threadIdx.x;
#pragma unroll
    for (int i = 0; i < 4; ++i) {
        int off  = tid * 16 + i * 4096;
        int row  = off >> 7;
        int slot = (off >> 4) & 7;
        int seg  = slot ^ (row & 7);
        load_lds16(A + (size_t)(m0 + row) * HIDc + k0 + seg * 8, (char*)lds + off);
    }
}

// ---------------------------------------------------------------------------
// 128x128 B^T MFMA GEMM core, K=768, BK=64. B-DIRECT variant:
// B fragments load straight from global (L2-hot 1.2MB weight panels) into
// registers — no B LDS, no B barrier gating. Only A is LDS-staged
// (32KB dbuf -> 3-4 blocks/CU vs R10's 2). Per iter:
//   {issue 8 B-frag reg loads(t); stage A(t+1) 4 loads; vmcnt(4)+bar;
//    ds_read A + MFMA(t); bar}
// vmcnt(4): B(t)+A(t) complete, A(t+1) (4 loads) stays in flight (counted).
// SWAP=0: acc row=m, col=n.  SWAP=1: swapped -> row=n, col=m.
// ---------------------------------------------------------------------------
template <int SWAP>
__device__ __forceinline__ void gemm128_bdir(
    const u16* __restrict__ A, const u16* __restrict__ Bt,
    int m0, int n0, u16* As, f32x4 (&acc)[4][4])
{
    const int lane = threadIdx.x & 63, wid = threadIdx.x >> 6;
    const int c16 = lane & 15, g = lane >> 4;
    const int wm = (wid >> 1) * 64, wn = (wid & 1) * 64;

    // per-lane B base: row n0+wn+c16 (tt adds 16-row steps), col g*8
    const u16* bbase = Bt + (size_t)(n0 + wn + c16) * HIDc + g * 8;

    stageA64(A, m0, 0, As);     // prologue -> buf 0
    int cur = 0;
    for (int t = 0; t < 12; ++t) {
        // B fragments for tile t: 8 x 16B per lane, direct from L2
        bf16x8 bf0[4], bf1[4];
        const u16* bt = bbase + t * 64;
#pragma unroll
        for (int tt = 0; tt < 4; ++tt) {
            bf0[tt] = *(const bf16x8*)(bt + (size_t)tt * 16 * HIDc);
            bf1[tt] = *(const bf16x8*)(bt + (size_t)tt * 16 * HIDc + 32);
        }
        if (t < 11) {
            stageA64(A, m0, (t + 1) * 64, As + (cur ^ 1) * 8192);
            VM_BAR(4);          // B(t), A(t) landed; A(t+1) in flight
        } else {
            VM_BAR(0);          // last tile: drain
        }
        const u16* Ab = As + cur * 8192;
#pragma unroll
        for (int kk = 0; kk < 2; ++kk) {
            bf16x8 af[4];
#pragma unroll
            for (int tt = 0; tt < 4; ++tt) {
                int ar = wm + tt * 16 + c16;
                int a8 = (kk * 4 + g) ^ (ar & 7);
                af[tt] = *(const bf16x8*)(Ab + ar * 64 + a8 * 8);
            }
            __builtin_amdgcn_s_setprio(1);
#pragma unroll
            for (int mt = 0; mt < 4; ++mt)
#pragma unroll
                for (int nt = 0; nt < 4; ++nt)
                    acc[mt][nt] = SWAP
                        ? __builtin_amdgcn_mfma_f32_16x16x32_bf16(
                              kk ? bf1[nt] : bf0[nt], af[mt], acc[mt][nt], 0, 0, 0)
                        : __builtin_amdgcn_mfma_f32_16x16x32_bf16(
                              af[mt], kk ? bf1[nt] : bf0[nt], acc[mt][nt], 0, 0, 0);
            __builtin_amdgcn_s_setprio(0);
        }
        BAR();                  // all waves done reading A buf cur
        cur ^= 1;
    }
}

// ---------------------------------------------------------------------------
// Merged QKV projection (z=0..2, 1152 blocks). B-direct core, 32KB LDS.
// z=0/1 (Q,K): SWAP=1 -> ushort4 store into [B,H,S,D] (Q scaled 1/8).
// z=2   (V) : SWAP=0 -> ushort4 store into transposed [B,H,D,S].
// ---------------------------------------------------------------------------
__global__ __launch_bounds__(256) void gemm_qkv_mfma(
    const u16* __restrict__ xb,
    const u16* __restrict__ wqt, const u16* __restrict__ wkt,
    const u16* __restrict__ wvt,
    const float* __restrict__ bq, const float* __restrict__ bk,
    const float* __restrict__ bv,
    u16* __restrict__ qg, u16* __restrict__ kg, u16* __restrict__ vtg)
{
    __shared__ u16 As[16384];            // 2 x 16KB A buffers
    const int z = blockIdx.z;
    const u16* Bt     = z == 0 ? wqt : z == 1 ? wkt : wvt;
    const float* bias = z == 0 ? bq : z == 1 ? bk : bv;

    const int m0 = blockIdx.x * 128, n0 = blockIdx.y * 128;
    f32x4 acc[4][4];
#pragma unroll
    for (int i = 0; i < 4; ++i)
#pragma unroll
        for (int j = 0; j < 4; ++j) acc[i][j] = (f32x4){0.f, 0.f, 0.f, 0.f};

    const int lane = threadIdx.x & 63, wid = threadIdx.x >> 6;
    const int c16 = lane & 15, g = lane >> 4;
    const int wm = (wid >> 1) * 64, wn = (wid & 1) * 64;

    if (z == 2) {
        gemm128_bdir<0>(xb, Bt, m0, n0, As, acc);
        // V epilogue: lane holds 4 consecutive m(=s) at fixed n(=d)
#pragma unroll
        for (int nt = 0; nt < 4; ++nt) {
            int n = n0 + wn + nt * 16 + c16;
            int h = n >> 6, d = n & 63;
            float bn = bias[n];
#pragma unroll
            for (int mt = 0; mt < 4; ++mt) {
                int m = m0 + wm + mt * 16 + g * 4;
                int b = m >> 12, s = m & (Sc - 1);
                size_t base = ((size_t)(b * Hc + h)) * Sc * Dc + (size_t)d * Sc + s;
                ushort4 pk;
                pk.x = to_bf16(acc[mt][nt][0] + bn);
                pk.y = to_bf16(acc[mt][nt][1] + bn);
                pk.z = to_bf16(acc[mt][nt][2] + bn);
                pk.w = to_bf16(acc[mt][nt][3] + bn);
                *(ushort4*)&vtg[base] = pk;
            }
        }
    } else {
        gemm128_bdir<1>(xb, Bt, m0, n0, As, acc);
        // Q/K epilogue: lane holds 4 consecutive n(=d) at fixed m(=s)
        const float scale = z ? 1.0f : 0.125f;
        u16* outp = z ? kg : qg;
#pragma unroll
        for (int mt = 0; mt < 4; ++mt) {
            int m = m0 + wm + mt * 16 + c16;
            int b = m >> 12, s = m & (Sc - 1);
            size_t rowbase = (size_t)(b * Hc) * Sc * Dc + (size_t)s * Dc;
#pragma unroll
            for (int nt = 0; nt < 4; ++nt) {
                int nb = n0 + wn + nt * 16 + g * 4;
                int h = nb >> 6, d0 = nb & 63;
                float4 b4 = *(const float4*)&bias[nb];
                ushort4 pk;
                pk.x = to_bf16((acc[mt][nt][0] + b4.x) * scale);
                pk.y = to_bf16((acc[mt][nt][1] + b4.y) * scale);
                pk.z = to_bf16((acc[mt][nt][2] + b4.z) * scale);
                pk.w = to_bf16((acc[mt][nt][3] + b4.w) * scale);
                *(ushort4*)&outp[rowbase + (size_t)h * Sc * Dc + d0] = pk;
            }
        }
    }
}

// ---------------------------------------------------------------------------
// Output projection + residual (SWAP=1, B-direct core): float4 x/y access.
// ---------------------------------------------------------------------------
__global__ __launch_bounds__(256) void gemm_proj_mfma(
    const u16* __restrict__ ctxb, const u16* __restrict__ wdt,
    const float* __restrict__ bd, const float* __restrict__ x,
    float* __restrict__ y)
{
    __shared__ u16 As[16384];
    const int m0 = blockIdx.x * 128, n0 = blockIdx.y * 128;
    f32x4 acc[4][4];
#pragma unroll
    for (int i = 0; i < 4; ++i)
#pragma unroll
        for (int j = 0; j < 4; ++j) acc[i][j] = (f32x4){0.f, 0.f, 0.f, 0.f};

    gemm128_bdir<1>(ctxb, wdt, m0, n0, As, acc);

    const int lane = threadIdx.x & 63, wid = threadIdx.x >> 6;
    const int c16 = lane & 15, g = lane >> 4;
    const int wm = (wid >> 1) * 64, wn = (wid & 1) * 64;

#pragma unroll
    for (int mt = 0; mt < 4; ++mt) {
        int m = m0 + wm + mt * 16 + c16;
#pragma unroll
        for (int nt = 0; nt < 4; ++nt) {
            int nb = n0 + wn + nt * 16 + g * 4;
            float4 b4 = *(const float4*)&bd[nb];
            float4 x4 = *(const float4*)&x[(size_t)m * HIDc + nb];
            float4 o4;
            o4.x = acc[mt][nt][0] + b4.x + x4.x;
            o4.y = acc[mt][nt][1] + b4.y + x4.y;
            o4.z = acc[mt][nt][2] + b4.z + x4.z;
            o4.w = acc[mt][nt][3] + b4.w + x4.w;
            *(float4*)&y[(size_t)m * HIDc + nb] = o4;
        }
    }
}

// ---------------------------------------------------------------------------
// MFMA banded attention v5 (unchanged): 128 queries/block, 8 waves,
// 384-row window, per-wave 18-tile band, pm overlays kwin, two-phase PV.
// ---------------------------------------------------------------------------
__global__ __launch_bounds__(512) void band_attn_mfma(
    const u16* __restrict__ qg, const u16* __restrict__ kg,
    const u16* __restrict__ vtg, const u16* __restrict__ zpad,
    u16* __restrict__ ctxb)
{
    extern __shared__ u16 sm[];
    u16* kwin = sm;            // [384][64] (49152B), swizzle seg^(row&7)
    u16* vt   = sm + 24576;    // [64][384], swizzle (sl&~7)|((sl^d)&7)
    u16* pm   = sm;            // [128][192-stride] overlay on kwin

    const int L = blockIdx.x;              // 0..767
    const int xcd = L & 7, tt = L >> 3;    // tt 0..95
    const int hb = xcd * 3 + (tt % 3);     // 0..23
    const int qc = tt / 3;                 // 0..31
    const int h = hb % Hc, b = hb / Hc;

    const int s0 = qc * QT3;
    const int tid = threadIdx.x;
    const int lane = tid & 63, w = tid >> 6;
    const int c16 = lane & 15, g = lane >> 4;
    const size_t hbase = ((size_t)(b * Hc + h)) * Sc * Dc;

    const u16* qp = &qg[hbase + (size_t)(s0 + w * 16 + c16) * Dc + g * 8];
    bf16x8 qa0 = *(const bf16x8*)qp;
    bf16x8 qa1 = *(const bf16x8*)(qp + 32);

#pragma unroll
    for (int i = 0; i < 6; ++i) {
        int c   = i * 8 + w;
        int row = c * 8 + (lane >> 3);
        int seg = (lane & 7) ^ (lane >> 3);
        int pos = s0 - Wc + row;
        const u16* src = (pos >= 0 && pos < Sc)
                       ? &kg[hbase + (size_t)pos * Dc + seg * 8] : zpad;
        load_lds16(src, (char*)kwin + c * 1024 + (lane & 63) * 16);
    }
#pragma unroll
    for (int i = 0; i < 6; ++i) {
        int c   = i * 8 + w;
        int idx = c * 64 + lane;
        int d   = idx / 48;
        int p   = idx - d * 48;
        int seg = (p & ~7) | ((p ^ d) & 7);
        int pos0 = s0 - Wc + seg * 8;
        const u16* src = (pos0 >= 0 && pos0 < Sc)
                       ? &vtg[hbase + (size_t)d * Sc + pos0] : zpad;
        load_lds16(src, (char*)vt + idx * 16);
    }

    VM_BAR(6);   // Q + kwin landed everywhere; vt's 6 loads still in flight

    const int tb  = w & ~1;
    const int off = (w & 1) * 16;
    f32x4 acc[NCT3];
#pragma unroll
    for (int ct = 0; ct < NCT3; ++ct) acc[ct] = (f32x4){0.f, 0.f, 0.f, 0.f};
    __builtin_amdgcn_s_setprio(1);
#pragma unroll
    for (int ct = 0; ct < NCT3; ++ct) {
        int row = (tb + ct) * 16 + c16;
        const u16* kb = kwin + row * 64;
        bf16x8 kb0 = *(const bf16x8*)(kb + (g       ^ (row & 7)) * 8);
        bf16x8 kb1 = *(const bf16x8*)(kb + ((g + 4) ^ (row & 7)) * 8);
        acc[ct] = __builtin_amdgcn_mfma_f32_16x16x32_bf16(qa0, kb0, acc[ct], 0, 0, 0);
        acc[ct] = __builtin_amdgcn_mfma_f32_16x16x32_bf16(qa1, kb1, acc[ct], 0, 0, 0);
    }
    __builtin_amdgcn_s_setprio(0);

    float mrow[4] = {-3e38f, -3e38f, -3e38f, -3e38f};
#pragma unroll
    for (int ct = 0; ct < NCT3; ++ct) {
#pragma unroll
        for (int r = 0; r < 4; ++r) {
            int ql  = g * 4 + r;
            int jl  = ct * 16 + c16 - off;
            int pos = s0 - Wc + (tb + ct) * 16 + c16;
            bool valid = (jl >= ql) && (jl <= ql + 2 * Wc) && (pos >= 0) && (pos < Sc);
            float v = valid ? acc[ct][r] : -3e38f;
            acc[ct][r] = v;
            mrow[r] = fmaxf(mrow[r], v);
        }
    }
#pragma unroll
    for (int r = 0; r < 4; ++r)
#pragma unroll
        for (int o2 = 1; o2 < 16; o2 <<= 1)
            mrow[r] = fmaxf(mrow[r], __shfl_xor(mrow[r], o2));

    float srow[4] = {0.f, 0.f, 0.f, 0.f};
#pragma unroll
    for (int ct = 0; ct < NCT3; ++ct)
#pragma unroll
        for (int r = 0; r < 4; ++r) {
            float e = __expf(acc[ct][r] - mrow[r]);
            acc[ct][r] = e;
            srow[r] += e;
        }
#pragma unroll
    for (int r = 0; r < 4; ++r)
#pragma unroll
        for (int o2 = 1; o2 < 16; o2 <<= 1)
            srow[r] += __shfl_xor(srow[r], o2);

    VM_BAR(0);   // all waves done reading kwin; vt fully landed

    float sq0 = __shfl(srow[0], (c16 >> 2) << 4);
    float sq1 = __shfl(srow[1], (c16 >> 2) << 4);
    float sq2 = __shfl(srow[2], (c16 >> 2) << 4);
    float sq3 = __shfl(srow[3], (c16 >> 2) << 4);
    int rr = c16 & 3;
    float sq = rr == 0 ? sq0 : rr == 1 ? sq1 : rr == 2 ? sq2 : sq3;
    float invq = 1.f / sq;

    const int qrow = w * 16 + c16;
    f32x4 o[4];
#pragma unroll
    for (int dt = 0; dt < 4; ++dt) o[dt] = (f32x4){0.f, 0.f, 0.f, 0.f};

    // ======== PV phase A: tiles 0..9 ========
#pragma unroll
    for (int ct = 0; ct < 10; ++ct)
#pragma unroll
        for (int r = 0; r < 4; ++r) {
            int q   = w * 16 + g * 4 + r;
            int col = ct * 16 + c16;
            int sl  = col >> 3;
            int ph  = (sl & ~7) | ((sl ^ q ^ (q >> 3)) & 7);
            pm[q * 192 + ph * 8 + (col & 7)] = to_bf16(acc[ct][r]);
        }
    __builtin_amdgcn_s_setprio(1);
#pragma unroll
    for (int ks = 0; ks < 5; ++ks) {
        int sl = ks * 4 + g;
        int ph = (sl & ~7) | ((sl ^ qrow ^ (qrow >> 3)) & 7);
        bf16x8 pa = *(const bf16x8*)(pm + qrow * 192 + ph * 8);
#pragma unroll
        for (int dt = 0; dt < 4; ++dt) {
            int d  = dt * 16 + c16;
            int vs = tb * 2 + ks * 4 + g;
            int pv = (vs & ~7) | ((vs ^ d) & 7);
            bf16x8 vb = *(const bf16x8*)(vt + d * 384 + pv * 8);
            o[dt] = __builtin_amdgcn_mfma_f32_16x16x32_bf16(vb, pa, o[dt], 0, 0, 0);
        }
    }
    __builtin_amdgcn_s_setprio(0);

    // ======== PV phase B: tiles 10..17 ========
#pragma unroll
    for (int ct = 10; ct < NCT3; ++ct)
#pragma unroll
        for (int r = 0; r < 4; ++r) {
            int q   = w * 16 + g * 4 + r;
            int col = ct * 16 + c16 - 160;
            int sl  = col >> 3;
            int ph  = (sl & ~7) | ((sl ^ q ^ (q >> 3)) & 7);
            pm[q * 192 + ph * 8 + (col & 7)] = to_bf16(acc[ct][r]);
        }
    __builtin_amdgcn_s_setprio(1);
#pragma unroll
    for (int ks = 0; ks < 4; ++ks) {
        int sl = ks * 4 + g;
        int ph = (sl & ~7) | ((sl ^ qrow ^ (qrow >> 3)) & 7);
        bf16x8 pa = *(const bf16x8*)(pm + qrow * 192 + ph * 8);
#pragma unroll
        for (int dt = 0; dt < 4; ++dt) {
            int d  = dt * 16 + c16;
            int vs = tb * 2 + 20 + ks * 4 + g;
            int pv = (vs & ~7) | ((vs ^ d) & 7);
            bf16x8 vb = *(const bf16x8*)(vt + d * 384 + pv * 8);
            o[dt] = __builtin_amdgcn_mfma_f32_16x16x32_bf16(vb, pa, o[dt], 0, 0, 0);
        }
    }
    __builtin_amdgcn_s_setprio(0);

    const size_t crow = ((size_t)(b * Sc + s0 + qrow)) * HIDc + h * Dc;
#pragma unroll
    for (int dt = 0; dt < 4; ++dt) {
        ushort4 pk;
        pk.x = to_bf16(o[dt][0] * invq);
        pk.y = to_bf16(o[dt][1] * invq);
        pk.z = to_bf16(o[dt][2] * invq);
        pk.w = to_bf16(o[dt][3] * invq);
        *(ushort4*)&ctxb[crow + dt * 16 + g * 4] = pk;
    }
}

// ---------------------------------------------------------------------------
// LayerNorm over last dim (768), block per row
// ---------------------------------------------------------------------------
__global__ __launch_bounds__(256) void ln_kernel(
    const float* __restrict__ y,
    const float* __restrict__ gamma, const float* __restrict__ beta,
    float* __restrict__ out)
{
    const int m = blockIdx.x;
    const float* row = y + (size_t)m * HIDc;
    const int t = threadIdx.x;
    float v0 = row[t], v1 = row[t + 256], v2 = row[t + 512];
    float s = v0 + v1 + v2;
    __shared__ float red[4];
    const int lane = t & 63, wid = t >> 6;
#pragma unroll
    for (int o = 1; o < 64; o <<= 1) s += __shfl_xor(s, o);
    if (lane == 0) red[wid] = s;
    __syncthreads();
    const float mu = (red[0] + red[1] + red[2] + red[3]) * (1.f / HIDc);
    v0 -= mu; v1 -= mu; v2 -= mu;
    float s2 = v0 * v0 + v1 * v1 + v2 * v2;
#pragma unroll
    for (int o = 1; o < 64; o <<= 1) s2 += __shfl_xor(s2, o);
    __syncthreads();
    if (lane == 0) red[wid] = s2;
    __syncthreads();
    const float var = (red[0] + red[1] + red[2] + red[3]) * (1.f / HIDc);
    const float rstd = rsqrtf(var + 1e-12f);
    const size_t base = (size_t)m * HIDc;
    out[base + t]       = v0 * rstd * gamma[t]       + beta[t];
    out[base + t + 256] = v1 * rstd * gamma[t + 256] + beta[t + 256];
    out[base + t + 512] = v2 * rstd * gamma[t + 512] + beta[t + 512];
}

// ---------------------------------------------------------------------------
extern "C" void kernel_launch(void* const* d_in, const int* in_sizes, int n_in,
                              void* d_out, int out_size, void* d_ws, size_t ws_size,
                              hipStream_t stream)
{
    const float* x     = (const float*)d_in[0];
    const float* Wq    = (const float*)d_in[1];
    const float* bq    = (const float*)d_in[2];
    const float* Wk    = (const float*)d_in[3];
    const float* bk    = (const float*)d_in[4];
    const float* Wv    = (const float*)d_in[5];
    const float* bv    = (const float*)d_in[6];
    const float* Wd    = (const float*)d_in[7];
    const float* bd    = (const float*)d_in[8];
    const float* gamma = (const float*)d_in[9];
    const float* beta  = (const float*)d_in[10];
    float* out = (float*)d_out;

    constexpr size_t CHUNK = (size_t)Mc * HIDc;      // 6,291,456
    constexpr size_t WSZ   = (size_t)HIDc * HIDc;    //   589,824
    u16* xb   = (u16*)d_ws;
    u16* wqt  = xb + CHUNK;
    u16* wkt  = wqt + WSZ;
    u16* wvt  = wkt + WSZ;
    u16* wdt  = wvt + WSZ;
    u16* qg   = wdt + WSZ;
    u16* kg   = qg + CHUNK;
    u16* vtg  = kg + CHUNK;
    u16* ctxb = vtg + CHUNK;
    float* yws = (float*)(ctxb + CHUNK);
    u16* zpad  = (u16*)(yws + CHUNK);   // 2KB zero guard (filled by prep_all)

    // 0) fused precision prep (x->bf16, W->Wt bf16, zpad)
    prep_all<<<6144 + 2304, 256, 0, stream>>>(
        x, xb, zpad, Wq, Wk, Wv, Wd, wqt, wkt, wvt, wdt);

    // 1) merged QKV projections (B-direct core, 32KB LDS, counted vmcnt)
    gemm_qkv_mfma<<<dim3(Mc / 128, HIDc / 128, 3), 256, 0, stream>>>(
        xb, wqt, wkt, wvt, bq, bk, bv, qg, kg, vtg);

    // 2) banded attention (v5: 128q/block, 8 waves, 96KB LDS)
    band_attn_mfma<<<dim3(Sc / QT3 * Hc * Bc), 512, 98304, stream>>>(
        qg, kg, vtg, zpad, ctxb);

    // 3) output projection + residual (B-direct core)
    gemm_proj_mfma<<<dim3(Mc / 128, HIDc / 128), 256, 0, stream>>>(
        ctxb, wdt, bd, x, yws);

    // 4) LayerNorm
    ln_kernel<<<Mc, 256, 0, stream>>>(yws, gamma, beta, out);
}

// Round 14
// 158.741 us; speedup vs baseline: 1.0414x; 1.0414x over previous
//
#include <hip/hip_runtime.h>
#include <math.h>

typedef unsigned short u16;
typedef __bf16 bf16x8 __attribute__((ext_vector_type(8)));
typedef float f32x4 __attribute__((ext_vector_type(4)));

// Problem constants
constexpr int Bc   = 2;
constexpr int Sc   = 4096;
constexpr int HIDc = 768;
constexpr int Hc   = 12;
constexpr int Dc   = 64;
constexpr int Wc   = 128;
constexpr int Mc   = Bc * Sc;

// attention tiling: 128 queries/block, 8 waves, per-wave 18-tile band
constexpr int QT3  = 128;
constexpr int NCT3 = 18;

#define VM_BAR(N) asm volatile("s_waitcnt vmcnt(" #N ")\n\ts_barrier" ::: "memory")
#define BAR()     asm volatile("s_barrier" ::: "memory")

static __device__ __forceinline__ void load_lds16(const void* g, void* l) {
    __builtin_amdgcn_global_load_lds(
        (const __attribute__((address_space(1))) void*)g,
        (__attribute__((address_space(3))) void*)l, 16, 0, 0);
}
static __device__ __forceinline__ u16 to_bf16(float f) {
    return __builtin_bit_cast(u16, (__bf16)f);
}

// ---------------------------------------------------------------------------
// Fused prep: blocks [0,6144): x fp32 -> bf16 (+ zpad fill in block 0);
// blocks [6144,8448): transpose W [K][N] fp32 -> Wt [N][K] bf16.
// ---------------------------------------------------------------------------
__global__ __launch_bounds__(256) void prep_all(
    const float* __restrict__ x, u16* __restrict__ xb, u16* __restrict__ zpad,
    const float* __restrict__ Wq, const float* __restrict__ Wk,
    const float* __restrict__ Wv, const float* __restrict__ Wd,
    u16* __restrict__ wqt, u16* __restrict__ wkt,
    u16* __restrict__ wvt, u16* __restrict__ wdt)
{
    const int bid = blockIdx.x;
    if (bid < 6144) {
        int i = bid * 256 + threadIdx.x;
        float4 v = ((const float4*)x)[i];
        ushort4 o;
        o.x = to_bf16(v.x); o.y = to_bf16(v.y);
        o.z = to_bf16(v.z); o.w = to_bf16(v.w);
        ((ushort4*)xb)[i] = o;
        if (bid == 0 && threadIdx.x < 128)
            ((int4*)zpad)[threadIdx.x] = make_int4(0, 0, 0, 0);  // 2KB zeros
    } else {
        int r = bid - 6144;                 // 0..2303
        int z = r / 576, xy = r - z * 576;  // 576 = 24*24 tiles per matrix
        const float* W = z == 0 ? Wq : z == 1 ? Wk : z == 2 ? Wv : Wd;
        u16* T         = z == 0 ? wqt : z == 1 ? wkt : z == 2 ? wvt : wdt;
        __shared__ float t[32][33];
        const int bx = (xy % 24) * 32, by = (xy / 24) * 32;
        const int tx = threadIdx.x & 31, ty = threadIdx.x >> 5;
#pragma unroll
        for (int i = 0; i < 32; i += 8)
            t[ty + i][tx] = W[(size_t)(by + ty + i) * HIDc + bx + tx];
        __syncthreads();
#pragma unroll
        for (int i = 0; i < 32; i += 8)
            T[(size_t)(bx + ty + i) * HIDc + by + tx] = to_bf16(t[tx][ty + i]);
    }
}

// ---------------------------------------------------------------------------
// BK=64 tile pair stager (R10 known-good): 128 rows x 64 k each for A, B^T.
// Row = 128B = 8 x 16B slots; swizzle slot8 = phys ^ (row&7).
// 8 global_load_lds per wave (4 A + 4 B) -> vmcnt unit = 8.
// ---------------------------------------------------------------------------
__device__ __forceinline__ void stage64(const u16* __restrict__ A,
                                        const u16* __restrict__ Bt,
                                        int m0, int n0, int k0,
                                        u16* As, u16* Bs, int soff)
{
#pragma unroll
    for (int i = 0; i < 4; ++i) {
        int off  = soff + i * 1024;
        int row  = off >> 7;
        int slot = (off >> 4) & 7;
        int seg  = slot ^ (row & 7);
        load_lds16(A  + (size_t)(m0 + row) * HIDc + k0 + seg * 8, (char*)As + off);
        load_lds16(Bt + (size_t)(n0 + row) * HIDc + k0 + seg * 8, (char*)Bs + off);
    }
}

// ---------------------------------------------------------------------------
// 128x128 B^T MFMA GEMM core, K=768, BK=64, double-buffered (64KB LDS) with
// COUNTED vmcnt: per iter {STAGE(t+1); vmcnt(8)+bar; ds_read+MFMA(t); bar}.
// R10 structure — best measured (55us merged qkv).
// SWAP=0: acc row=m, col=n.  SWAP=1: operands swapped -> row=n, col=m.
// ---------------------------------------------------------------------------
template <int SWAP>
__device__ __forceinline__ void gemm128_core(
    const u16* __restrict__ A, const u16* __restrict__ Bt,
    int m0, int n0, u16* As, u16* Bs, f32x4 (&acc)[4][4])
{
    const int lane = threadIdx.x & 63, wid = threadIdx.x >> 6;
    const int c16 = lane & 15, g = lane >> 4;
    const int wm = (wid >> 1) * 64, wn = (wid & 1) * 64;
    const int soff = wid * 4096 + lane * 16;

    stage64(A, Bt, m0, n0, 0, As, Bs, soff);
    int cur = 0;
    for (int t = 0; t < 12; ++t) {
        if (t < 11) {
            stage64(A, Bt, m0, n0, (t + 1) * 64,
                    As + (cur ^ 1) * 8192, Bs + (cur ^ 1) * 8192, soff);
            VM_BAR(8);          // stage(t) landed; stage(t+1) in flight
        } else {
            VM_BAR(0);
        }
        const u16* Ab = As + cur * 8192;
        const u16* Bb = Bs + cur * 8192;
#pragma unroll
        for (int kk = 0; kk < 2; ++kk) {
            bf16x8 af[4], bfr[4];
#pragma unroll
            for (int tt = 0; tt < 4; ++tt) {
                int ar = wm + tt * 16 + c16;
                int a8 = (kk * 4 + g) ^ (ar & 7);
                af[tt] = *(const bf16x8*)(Ab + ar * 64 + a8 * 8);
                int br = wn + tt * 16 + c16;
                int b8 = (kk * 4 + g) ^ (br & 7);
                bfr[tt] = *(const bf16x8*)(Bb + br * 64 + b8 * 8);
            }
            __builtin_amdgcn_s_setprio(1);
#pragma unroll
            for (int mt = 0; mt < 4; ++mt)
#pragma unroll
                for (int nt = 0; nt < 4; ++nt)
                    acc[mt][nt] = SWAP
                        ? __builtin_amdgcn_mfma_f32_16x16x32_bf16(
                              bfr[nt], af[mt], acc[mt][nt], 0, 0, 0)
                        : __builtin_amdgcn_mfma_f32_16x16x32_bf16(
                              af[mt], bfr[nt], acc[mt][nt], 0, 0, 0);
            __builtin_amdgcn_s_setprio(0);
        }
        BAR();
        cur ^= 1;
    }
}

// ---------------------------------------------------------------------------
// Merged QKV projection (z=0..2, 1152 blocks; R10 known-good).
// z=0/1 (Q,K): SWAP=1 -> ushort4 store into [B,H,S,D] (Q scaled 1/8).
// z=2   (V) : SWAP=0 -> ushort4 store into transposed [B,H,D,S].
// ---------------------------------------------------------------------------
__global__ __launch_bounds__(256) void gemm_qkv_mfma(
    const u16* __restrict__ xb,
    const u16* __restrict__ wqt, const u16* __restrict__ wkt,
    const u16* __restrict__ wvt,
    const float* __restrict__ bq, const float* __restrict__ bk,
    const float* __restrict__ bv,
    u16* __restrict__ qg, u16* __restrict__ kg, u16* __restrict__ vtg)
{
    __shared__ u16 As[16384], Bs[16384];
    const int z = blockIdx.z;
    const u16* Bt     = z == 0 ? wqt : z == 1 ? wkt : wvt;
    const float* bias = z == 0 ? bq : z == 1 ? bk : bv;

    const int m0 = blockIdx.x * 128, n0 = blockIdx.y * 128;
    f32x4 acc[4][4];
#pragma unroll
    for (int i = 0; i < 4; ++i)
#pragma unroll
        for (int j = 0; j < 4; ++j) acc[i][j] = (f32x4){0.f, 0.f, 0.f, 0.f};

    const int lane = threadIdx.x & 63, wid = threadIdx.x >> 6;
    const int c16 = lane & 15, g = lane >> 4;
    const int wm = (wid >> 1) * 64, wn = (wid & 1) * 64;

    if (z == 2) {
        gemm128_core<0>(xb, Bt, m0, n0, As, Bs, acc);
#pragma unroll
        for (int nt = 0; nt < 4; ++nt) {
            int n = n0 + wn + nt * 16 + c16;
            int h = n >> 6, d = n & 63;
            float bn = bias[n];
#pragma unroll
            for (int mt = 0; mt < 4; ++mt) {
                int m = m0 + wm + mt * 16 + g * 4;
                int b = m >> 12, s = m & (Sc - 1);
                size_t base = ((size_t)(b * Hc + h)) * Sc * Dc + (size_t)d * Sc + s;
                ushort4 pk;
                pk.x = to_bf16(acc[mt][nt][0] + bn);
                pk.y = to_bf16(acc[mt][nt][1] + bn);
                pk.z = to_bf16(acc[mt][nt][2] + bn);
                pk.w = to_bf16(acc[mt][nt][3] + bn);
                *(ushort4*)&vtg[base] = pk;
            }
        }
    } else {
        gemm128_core<1>(xb, Bt, m0, n0, As, Bs, acc);
        const float scale = z ? 1.0f : 0.125f;
        u16* outp = z ? kg : qg;
#pragma unroll
        for (int mt = 0; mt < 4; ++mt) {
            int m = m0 + wm + mt * 16 + c16;
            int b = m >> 12, s = m & (Sc - 1);
            size_t rowbase = (size_t)(b * Hc) * Sc * Dc + (size_t)s * Dc;
#pragma unroll
            for (int nt = 0; nt < 4; ++nt) {
                int nb = n0 + wn + nt * 16 + g * 4;
                int h = nb >> 6, d0 = nb & 63;
                float4 b4 = *(const float4*)&bias[nb];
                ushort4 pk;
                pk.x = to_bf16((acc[mt][nt][0] + b4.x) * scale);
                pk.y = to_bf16((acc[mt][nt][1] + b4.y) * scale);
                pk.z = to_bf16((acc[mt][nt][2] + b4.z) * scale);
                pk.w = to_bf16((acc[mt][nt][3] + b4.w) * scale);
                *(ushort4*)&outp[rowbase + (size_t)h * Sc * Dc + d0] = pk;
            }
        }
    }
}

// ---------------------------------------------------------------------------
// Output projection + residual (SWAP=1, R10 core): float4 x/y access.
// ---------------------------------------------------------------------------
__global__ __launch_bounds__(256) void gemm_proj_mfma(
    const u16* __restrict__ ctxb, const u16* __restrict__ wdt,
    const float* __restrict__ bd, const float* __restrict__ x,
    float* __restrict__ y)
{
    __shared__ u16 As[16384], Bs[16384];
    const int m0 = blockIdx.x * 128, n0 = blockIdx.y * 128;
    f32x4 acc[4][4];
#pragma unroll
    for (int i = 0; i < 4; ++i)
#pragma unroll
        for (int j = 0; j < 4; ++j) acc[i][j] = (f32x4){0.f, 0.f, 0.f, 0.f};

    gemm128_core<1>(ctxb, wdt, m0, n0, As, Bs, acc);

    const int lane = threadIdx.x & 63, wid = threadIdx.x >> 6;
    const int c16 = lane & 15, g = lane >> 4;
    const int wm = (wid >> 1) * 64, wn = (wid & 1) * 64;

#pragma unroll
    for (int mt = 0; mt < 4; ++mt) {
        int m = m0 + wm + mt * 16 + c16;
#pragma unroll
        for (int nt = 0; nt < 4; ++nt) {
            int nb = n0 + wn + nt * 16 + g * 4;
            float4 b4 = *(const float4*)&bd[nb];
            float4 x4 = *(const float4*)&x[(size_t)m * HIDc + nb];
            float4 o4;
            o4.x = acc[mt][nt][0] + b4.x + x4.x;
            o4.y = acc[mt][nt][1] + b4.y + x4.y;
            o4.z = acc[mt][nt][2] + b4.z + x4.z;
            o4.w = acc[mt][nt][3] + b4.w + x4.w;
            *(float4*)&y[(size_t)m * HIDc + nb] = o4;
        }
    }
}

// ---------------------------------------------------------------------------
// MFMA banded attention v6: BARRIER-FREE. K and V fragments read DIRECT from
// global (L2-hot, XCD-clustered; 16 rows x one full 64B line per wave read).
// LDS = pm only (48KB static, wave-private rows -> no cross-wave sync at all).
// __launch_bounds__(512,4) -> 2 blocks/CU = 16 waves/CU (2x v5's TLP).
// Garbage-K at window edges is masked before softmax; OOB-V clamped to zpad.
// All OOB K reads stay inside d_ws (qg|kg|vtg contiguous) — no fault.
// ---------------------------------------------------------------------------
__global__ __launch_bounds__(512, 4) void band_attn_mfma(
    const u16* __restrict__ qg, const u16* __restrict__ kg,
    const u16* __restrict__ vtg, const u16* __restrict__ zpad,
    u16* __restrict__ ctxb)
{
    __shared__ u16 pm[128 * 192];          // 49152 B

    const int L = blockIdx.x;              // 0..767
    const int xcd = L & 7, tt = L >> 3;    // tt 0..95
    const int hb = xcd * 3 + (tt % 3);     // 0..23
    const int qc = tt / 3;                 // 0..31
    const int h = hb % Hc, b = hb / Hc;

    const int s0 = qc * QT3;
    const int tid = threadIdx.x;
    const int lane = tid & 63, w = tid >> 6;
    const int c16 = lane & 15, g = lane >> 4;
    const size_t hbase = ((size_t)(b * Hc + h)) * Sc * Dc;

    // Q fragments
    const u16* qp = &qg[hbase + (size_t)(s0 + w * 16 + c16) * Dc + g * 8];
    bf16x8 qa0 = *(const bf16x8*)qp;
    bf16x8 qa1 = *(const bf16x8*)(qp + 32);

    const int tb  = w & ~1;
    const int off = (w & 1) * 16;

    // --- QK^T: direct global K-fragment reads ---
    f32x4 acc[NCT3];
#pragma unroll
    for (int ct = 0; ct < NCT3; ++ct) acc[ct] = (f32x4){0.f, 0.f, 0.f, 0.f};
    __builtin_amdgcn_s_setprio(1);
#pragma unroll
    for (int ct = 0; ct < NCT3; ++ct) {
        int pos = s0 - Wc + (tb + ct) * 16 + c16;
        const u16* kp = kg + hbase + (size_t)pos * Dc + g * 8;
        bf16x8 kb0 = *(const bf16x8*)kp;
        bf16x8 kb1 = *(const bf16x8*)(kp + 32);
        acc[ct] = __builtin_amdgcn_mfma_f32_16x16x32_bf16(qa0, kb0, acc[ct], 0, 0, 0);
        acc[ct] = __builtin_amdgcn_mfma_f32_16x16x32_bf16(qa1, kb1, acc[ct], 0, 0, 0);
    }
    __builtin_amdgcn_s_setprio(0);

    // --- mask + row max (replaces any garbage at invalid cols) ---
    float mrow[4] = {-3e38f, -3e38f, -3e38f, -3e38f};
#pragma unroll
    for (int ct = 0; ct < NCT3; ++ct) {
#pragma unroll
        for (int r = 0; r < 4; ++r) {
            int ql  = g * 4 + r;
            int jl  = ct * 16 + c16 - off;
            int pos = s0 - Wc + (tb + ct) * 16 + c16;
            bool valid = (jl >= ql) && (jl <= ql + 2 * Wc) && (pos >= 0) && (pos < Sc);
            float v = valid ? acc[ct][r] : -3e38f;
            acc[ct][r] = v;
            mrow[r] = fmaxf(mrow[r], v);
        }
    }
#pragma unroll
    for (int r = 0; r < 4; ++r)
#pragma unroll
        for (int o2 = 1; o2 < 16; o2 <<= 1)
            mrow[r] = fmaxf(mrow[r], __shfl_xor(mrow[r], o2));

    // --- exp + row sum (masked -> exactly 0) ---
    float srow[4] = {0.f, 0.f, 0.f, 0.f};
#pragma unroll
    for (int ct = 0; ct < NCT3; ++ct)
#pragma unroll
        for (int r = 0; r < 4; ++r) {
            float e = __expf(acc[ct][r] - mrow[r]);
            acc[ct][r] = e;
            srow[r] += e;
        }
#pragma unroll
    for (int r = 0; r < 4; ++r)
#pragma unroll
        for (int o2 = 1; o2 < 16; o2 <<= 1)
            srow[r] += __shfl_xor(srow[r], o2);

    // --- 1/sum for this lane's output query q = w*16 + c16 ---
    float sq0 = __shfl(srow[0], (c16 >> 2) << 4);
    float sq1 = __shfl(srow[1], (c16 >> 2) << 4);
    float sq2 = __shfl(srow[2], (c16 >> 2) << 4);
    float sq3 = __shfl(srow[3], (c16 >> 2) << 4);
    int rr = c16 & 3;
    float sq = rr == 0 ? sq0 : rr == 1 ? sq1 : rr == 2 ? sq2 : sq3;
    float invq = 1.f / sq;

    const int qrow = w * 16 + c16;
    f32x4 o[4];
#pragma unroll
    for (int dt = 0; dt < 4; ++dt) o[dt] = (f32x4){0.f, 0.f, 0.f, 0.f};

    // ======== PV phase A: tiles 0..9 (wave-window keys 0..159) ========
#pragma unroll
    for (int ct = 0; ct < 10; ++ct)
#pragma unroll
        for (int r = 0; r < 4; ++r) {
            int q   = w * 16 + g * 4 + r;
            int col = ct * 16 + c16;
            int sl  = col >> 3;
            int ph  = (sl & ~7) | ((sl ^ q ^ (q >> 3)) & 7);
            pm[q * 192 + ph * 8 + (col & 7)] = to_bf16(acc[ct][r]);
        }
    __builtin_amdgcn_s_setprio(1);
#pragma unroll
    for (int ks = 0; ks < 5; ++ks) {
        int sl = ks * 4 + g;
        int ph = (sl & ~7) | ((sl ^ qrow ^ (qrow >> 3)) & 7);
        bf16x8 pa = *(const bf16x8*)(pm + qrow * 192 + ph * 8);
        int vs   = tb * 2 + sl;
        int pos0 = s0 - Wc + vs * 8;
        bool ok  = (pos0 >= 0) && (pos0 <= Sc - 8);
#pragma unroll
        for (int dt = 0; dt < 4; ++dt) {
            int d = dt * 16 + c16;
            const u16* vp = ok ? (vtg + hbase + (size_t)d * Sc + pos0) : zpad;
            bf16x8 vb = *(const bf16x8*)vp;
            o[dt] = __builtin_amdgcn_mfma_f32_16x16x32_bf16(vb, pa, o[dt], 0, 0, 0);
        }
    }
    __builtin_amdgcn_s_setprio(0);

    // ======== PV phase B: tiles 10..17 (keys 160..287) ========
#pragma unroll
    for (int ct = 10; ct < NCT3; ++ct)
#pragma unroll
        for (int r = 0; r < 4; ++r) {
            int q   = w * 16 + g * 4 + r;
            int col = ct * 16 + c16 - 160;
            int sl  = col >> 3;
            int ph  = (sl & ~7) | ((sl ^ q ^ (q >> 3)) & 7);
            pm[q * 192 + ph * 8 + (col & 7)] = to_bf16(acc[ct][r]);
        }
    __builtin_amdgcn_s_setprio(1);
#pragma unroll
    for (int ks = 0; ks < 4; ++ks) {
        int sl = ks * 4 + g;
        int ph = (sl & ~7) | ((sl ^ qrow ^ (qrow >> 3)) & 7);
        bf16x8 pa = *(const bf16x8*)(pm + qrow * 192 + ph * 8);
        int vs   = tb * 2 + 20 + sl;
        int pos0 = s0 - Wc + vs * 8;
        bool ok  = (pos0 >= 0) && (pos0 <= Sc - 8);
#pragma unroll
        for (int dt = 0; dt < 4; ++dt) {
            int d = dt * 16 + c16;
            const u16* vp = ok ? (vtg + hbase + (size_t)d * Sc + pos0) : zpad;
            bf16x8 vb = *(const bf16x8*)vp;
            o[dt] = __builtin_amdgcn_mfma_f32_16x16x32_bf16(vb, pa, o[dt], 0, 0, 0);
        }
    }
    __builtin_amdgcn_s_setprio(0);

    // --- ctx store: ushort4 at [s=s0+qrow][h*64 + dt*16 + g*4] ---
    const size_t crow = ((size_t)(b * Sc + s0 + qrow)) * HIDc + h * Dc;
#pragma unroll
    for (int dt = 0; dt < 4; ++dt) {
        ushort4 pk;
        pk.x = to_bf16(o[dt][0] * invq);
        pk.y = to_bf16(o[dt][1] * invq);
        pk.z = to_bf16(o[dt][2] * invq);
        pk.w = to_bf16(o[dt][3] * invq);
        *(ushort4*)&ctxb[crow + dt * 16 + g * 4] = pk;
    }
}

// ---------------------------------------------------------------------------
// LayerNorm over last dim (768), block per row
// ---------------------------------------------------------------------------
__global__ __launch_bounds__(256) void ln_kernel(
    const float* __restrict__ y,
    const float* __restrict__ gamma, const float* __restrict__ beta,
    float* __restrict__ out)
{
    const int m = blockIdx.x;
    const float* row = y + (size_t)m * HIDc;
    const int t = threadIdx.x;
    float v0 = row[t], v1 = row[t + 256], v2 = row[t + 512];
    float s = v0 + v1 + v2;
    __shared__ float red[4];
    const int lane = t & 63, wid = t >> 6;
#pragma unroll
    for (int o = 1; o < 64; o <<= 1) s += __shfl_xor(s, o);
    if (lane == 0) red[wid] = s;
    __syncthreads();
    const float mu = (red[0] + red[1] + red[2] + red[3]) * (1.f / HIDc);
    v0 -= mu; v1 -= mu; v2 -= mu;
    float s2 = v0 * v0 + v1 * v1 + v2 * v2;
#pragma unroll
    for (int o = 1; o < 64; o <<= 1) s2 += __shfl_xor(s2, o);
    __syncthreads();
    if (lane == 0) red[wid] = s2;
    __syncthreads();
    const float var = (red[0] + red[1] + red[2] + red[3]) * (1.f / HIDc);
    const float rstd = rsqrtf(var + 1e-12f);
    const size_t base = (size_t)m * HIDc;
    out[base + t]       = v0 * rstd * gamma[t]       + beta[t];
    out[base + t + 256] = v1 * rstd * gamma[t + 256] + beta[t + 256];
    out[base + t + 512] = v2 * rstd * gamma[t + 512] + beta[t + 512];
}

// ---------------------------------------------------------------------------
extern "C" void kernel_launch(void* const* d_in, const int* in_sizes, int n_in,
                              void* d_out, int out_size, void* d_ws, size_t ws_size,
                              hipStream_t stream)
{
    const float* x     = (const float*)d_in[0];
    const float* Wq    = (const float*)d_in[1];
    const float* bq    = (const float*)d_in[2];
    const float* Wk    = (const float*)d_in[3];
    const float* bk    = (const float*)d_in[4];
    const float* Wv    = (const float*)d_in[5];
    const float* bv    = (const float*)d_in[6];
    const float* Wd    = (const float*)d_in[7];
    const float* bd    = (const float*)d_in[8];
    const float* gamma = (const float*)d_in[9];
    const float* beta  = (const float*)d_in[10];
    float* out = (float*)d_out;

    constexpr size_t CHUNK = (size_t)Mc * HIDc;      // 6,291,456
    constexpr size_t WSZ   = (size_t)HIDc * HIDc;    //   589,824
    u16* xb   = (u16*)d_ws;
    u16* wqt  = xb + CHUNK;
    u16* wkt  = wqt + WSZ;
    u16* wvt  = wkt + WSZ;
    u16* wdt  = wvt + WSZ;
    u16* qg   = wdt + WSZ;
    u16* kg   = qg + CHUNK;
    u16* vtg  = kg + CHUNK;
    u16* ctxb = vtg + CHUNK;
    float* yws = (float*)(ctxb + CHUNK);
    u16* zpad  = (u16*)(yws + CHUNK);   // 2KB zero guard (filled by prep_all)

    // 0) fused precision prep (x->bf16, W->Wt bf16, zpad)
    prep_all<<<6144 + 2304, 256, 0, stream>>>(
        x, xb, zpad, Wq, Wk, Wv, Wd, wqt, wkt, wvt, wdt);

    // 1) merged QKV projections (R10 core: BK=64 dbuf, counted vmcnt)
    gemm_qkv_mfma<<<dim3(Mc / 128, HIDc / 128, 3), 256, 0, stream>>>(
        xb, wqt, wkt, wvt, bq, bk, bv, qg, kg, vtg);

    // 2) banded attention v6 (barrier-free, direct K/V, 48KB LDS, 2 blk/CU)
    band_attn_mfma<<<dim3(Sc / QT3 * Hc * Bc), 512, 0, stream>>>(
        qg, kg, vtg, zpad, ctxb);

    // 3) output projection + residual (R10 core)
    gemm_proj_mfma<<<dim3(Mc / 128, HIDc / 128), 256, 0, stream>>>(
        ctxb, wdt, bd, x, yws);

    // 4) LayerNorm
    ln_kernel<<<Mc, 256, 0, stream>>>(yws, gamma, beta, out);
}

// Round 15
// 123.538 us; speedup vs baseline: 1.3382x; 1.2849x over previous
//
#include <hip/hip_runtime.h>
#include <math.h>

typedef unsigned short u16;
typedef __bf16 bf16x8 __attribute__((ext_vector_type(8)));
typedef float f32x4 __attribute__((ext_vector_type(4)));

// Problem constants
constexpr int Bc   = 2;
constexpr int Sc   = 4096;
constexpr int HIDc = 768;
constexpr int Hc   = 12;
constexpr int Dc   = 64;
constexpr int Wc   = 128;
constexpr int Mc   = Bc * Sc;

// attention tiling (v5): 128 queries/block, 8 waves, per-wave 18-tile band
constexpr int QT3  = 128;
constexpr int NCT3 = 18;

#define VM_BAR(N) asm volatile("s_waitcnt vmcnt(" #N ")\n\ts_barrier" ::: "memory")
#define BAR()     asm volatile("s_barrier" ::: "memory")

static __device__ __forceinline__ void load_lds16(const void* g, void* l) {
    __builtin_amdgcn_global_load_lds(
        (const __attribute__((address_space(1))) void*)g,
        (__attribute__((address_space(3))) void*)l, 16, 0, 0);
}
static __device__ __forceinline__ u16 to_bf16(float f) {
    return __builtin_bit_cast(u16, (__bf16)f);
}

// ---------------------------------------------------------------------------
// Fused prep: blocks [0,6144): x fp32 -> bf16 (+ zpad fill in block 0);
// blocks [6144,8448): transpose W [K][N] fp32 -> Wt [N][K] bf16.
// ---------------------------------------------------------------------------
__global__ __launch_bounds__(256) void prep_all(
    const float* __restrict__ x, u16* __restrict__ xb, u16* __restrict__ zpad,
    const float* __restrict__ Wq, const float* __restrict__ Wk,
    const float* __restrict__ Wv, const float* __restrict__ Wd,
    u16* __restrict__ wqt, u16* __restrict__ wkt,
    u16* __restrict__ wvt, u16* __restrict__ wdt)
{
    const int bid = blockIdx.x;
    if (bid < 6144) {
        int i = bid * 256 + threadIdx.x;
        float4 v = ((const float4*)x)[i];
        ushort4 o;
        o.x = to_bf16(v.x); o.y = to_bf16(v.y);
        o.z = to_bf16(v.z); o.w = to_bf16(v.w);
        ((ushort4*)xb)[i] = o;
        if (bid == 0 && threadIdx.x < 128)
            ((int4*)zpad)[threadIdx.x] = make_int4(0, 0, 0, 0);  // 2KB zeros
    } else {
        int r = bid - 6144;                 // 0..2303
        int z = r / 576, xy = r - z * 576;  // 576 = 24*24 tiles per matrix
        const float* W = z == 0 ? Wq : z == 1 ? Wk : z == 2 ? Wv : Wd;
        u16* T         = z == 0 ? wqt : z == 1 ? wkt : z == 2 ? wvt : wdt;
        __shared__ float t[32][33];
        const int bx = (xy % 24) * 32, by = (xy / 24) * 32;
        const int tx = threadIdx.x & 31, ty = threadIdx.x >> 5;
#pragma unroll
        for (int i = 0; i < 32; i += 8)
            t[ty + i][tx] = W[(size_t)(by + ty + i) * HIDc + bx + tx];
        __syncthreads();
#pragma unroll
        for (int i = 0; i < 32; i += 8)
            T[(size_t)(bx + ty + i) * HIDc + by + tx] = to_bf16(t[tx][ty + i]);
    }
}

// ---------------------------------------------------------------------------
// BK=64 tile pair stager (R10 known-good): 128 rows x 64 k each for A, B^T.
// Row = 128B = 8 x 16B slots; swizzle slot8 = phys ^ (row&7).
// 8 global_load_lds per wave (4 A + 4 B) -> vmcnt unit = 8.
// ---------------------------------------------------------------------------
__device__ __forceinline__ void stage64(const u16* __restrict__ A,
                                        const u16* __restrict__ Bt,
                                        int m0, int n0, int k0,
                                        u16* As, u16* Bs, int soff)
{
#pragma unroll
    for (int i = 0; i < 4; ++i) {
        int off  = soff + i * 1024;
        int row  = off >> 7;
        int slot = (off >> 4) & 7;
        int seg  = slot ^ (row & 7);
        load_lds16(A  + (size_t)(m0 + row) * HIDc + k0 + seg * 8, (char*)As + off);
        load_lds16(Bt + (size_t)(n0 + row) * HIDc + k0 + seg * 8, (char*)Bs + off);
    }
}

// ---------------------------------------------------------------------------
// 128x128 B^T MFMA GEMM core, K=768, BK=64, double-buffered (64KB LDS) with
// COUNTED vmcnt: per iter {STAGE(t+1); vmcnt(8)+bar; ds_read+MFMA(t); bar}.
// Empirical local optimum for this K=768 family: BK32-drain (R5), BK32-counted
// (R9), 256x128 3-stage ring (R11), B-direct (R12) all regressed.
// SWAP=0: acc row=m, col=n.  SWAP=1: operands swapped -> row=n, col=m.
// ---------------------------------------------------------------------------
template <int SWAP>
__device__ __forceinline__ void gemm128_core(
    const u16* __restrict__ A, const u16* __restrict__ Bt,
    int m0, int n0, u16* As, u16* Bs, f32x4 (&acc)[4][4])
{
    const int lane = threadIdx.x & 63, wid = threadIdx.x >> 6;
    const int c16 = lane & 15, g = lane >> 4;
    const int wm = (wid >> 1) * 64, wn = (wid & 1) * 64;
    const int soff = wid * 4096 + lane * 16;

    stage64(A, Bt, m0, n0, 0, As, Bs, soff);
    int cur = 0;
    for (int t = 0; t < 12; ++t) {
        if (t < 11) {
            stage64(A, Bt, m0, n0, (t + 1) * 64,
                    As + (cur ^ 1) * 8192, Bs + (cur ^ 1) * 8192, soff);
            VM_BAR(8);          // stage(t) landed; stage(t+1) in flight
        } else {
            VM_BAR(0);
        }
        const u16* Ab = As + cur * 8192;
        const u16* Bb = Bs + cur * 8192;
#pragma unroll
        for (int kk = 0; kk < 2; ++kk) {
            bf16x8 af[4], bfr[4];
#pragma unroll
            for (int tt = 0; tt < 4; ++tt) {
                int ar = wm + tt * 16 + c16;
                int a8 = (kk * 4 + g) ^ (ar & 7);
                af[tt] = *(const bf16x8*)(Ab + ar * 64 + a8 * 8);
                int br = wn + tt * 16 + c16;
                int b8 = (kk * 4 + g) ^ (br & 7);
                bfr[tt] = *(const bf16x8*)(Bb + br * 64 + b8 * 8);
            }
            __builtin_amdgcn_s_setprio(1);
#pragma unroll
            for (int mt = 0; mt < 4; ++mt)
#pragma unroll
                for (int nt = 0; nt < 4; ++nt)
                    acc[mt][nt] = SWAP
                        ? __builtin_amdgcn_mfma_f32_16x16x32_bf16(
                              bfr[nt], af[mt], acc[mt][nt], 0, 0, 0)
                        : __builtin_amdgcn_mfma_f32_16x16x32_bf16(
                              af[mt], bfr[nt], acc[mt][nt], 0, 0, 0);
            __builtin_amdgcn_s_setprio(0);
        }
        BAR();
        cur ^= 1;
    }
}

// ---------------------------------------------------------------------------
// Merged QKV projection (z=0..2, 1152 blocks; R10 known-good).
// z=0/1 (Q,K): SWAP=1 -> ushort4 store into [B,H,S,D] (Q scaled 1/8).
// z=2   (V) : SWAP=0 -> ushort4 store into transposed [B,H,D,S].
// ---------------------------------------------------------------------------
__global__ __launch_bounds__(256) void gemm_qkv_mfma(
    const u16* __restrict__ xb,
    const u16* __restrict__ wqt, const u16* __restrict__ wkt,
    const u16* __restrict__ wvt,
    const float* __restrict__ bq, const float* __restrict__ bk,
    const float* __restrict__ bv,
    u16* __restrict__ qg, u16* __restrict__ kg, u16* __restrict__ vtg)
{
    __shared__ u16 As[16384], Bs[16384];
    const int z = blockIdx.z;
    const u16* Bt     = z == 0 ? wqt : z == 1 ? wkt : wvt;
    const float* bias = z == 0 ? bq : z == 1 ? bk : bv;

    const int m0 = blockIdx.x * 128, n0 = blockIdx.y * 128;
    f32x4 acc[4][4];
#pragma unroll
    for (int i = 0; i < 4; ++i)
#pragma unroll
        for (int j = 0; j < 4; ++j) acc[i][j] = (f32x4){0.f, 0.f, 0.f, 0.f};

    const int lane = threadIdx.x & 63, wid = threadIdx.x >> 6;
    const int c16 = lane & 15, g = lane >> 4;
    const int wm = (wid >> 1) * 64, wn = (wid & 1) * 64;

    if (z == 2) {
        gemm128_core<0>(xb, Bt, m0, n0, As, Bs, acc);
#pragma unroll
        for (int nt = 0; nt < 4; ++nt) {
            int n = n0 + wn + nt * 16 + c16;
            int h = n >> 6, d = n & 63;
            float bn = bias[n];
#pragma unroll
            for (int mt = 0; mt < 4; ++mt) {
                int m = m0 + wm + mt * 16 + g * 4;
                int b = m >> 12, s = m & (Sc - 1);
                size_t base = ((size_t)(b * Hc + h)) * Sc * Dc + (size_t)d * Sc + s;
                ushort4 pk;
                pk.x = to_bf16(acc[mt][nt][0] + bn);
                pk.y = to_bf16(acc[mt][nt][1] + bn);
                pk.z = to_bf16(acc[mt][nt][2] + bn);
                pk.w = to_bf16(acc[mt][nt][3] + bn);
                *(ushort4*)&vtg[base] = pk;
            }
        }
    } else {
        gemm128_core<1>(xb, Bt, m0, n0, As, Bs, acc);
        const float scale = z ? 1.0f : 0.125f;
        u16* outp = z ? kg : qg;
#pragma unroll
        for (int mt = 0; mt < 4; ++mt) {
            int m = m0 + wm + mt * 16 + c16;
            int b = m >> 12, s = m & (Sc - 1);
            size_t rowbase = (size_t)(b * Hc) * Sc * Dc + (size_t)s * Dc;
#pragma unroll
            for (int nt = 0; nt < 4; ++nt) {
                int nb = n0 + wn + nt * 16 + g * 4;
                int h = nb >> 6, d0 = nb & 63;
                float4 b4 = *(const float4*)&bias[nb];
                ushort4 pk;
                pk.x = to_bf16((acc[mt][nt][0] + b4.x) * scale);
                pk.y = to_bf16((acc[mt][nt][1] + b4.y) * scale);
                pk.z = to_bf16((acc[mt][nt][2] + b4.z) * scale);
                pk.w = to_bf16((acc[mt][nt][3] + b4.w) * scale);
                *(ushort4*)&outp[rowbase + (size_t)h * Sc * Dc + d0] = pk;
            }
        }
    }
}

// ---------------------------------------------------------------------------
// Output projection + residual (SWAP=1, R10 core): float4 x/y access.
// ---------------------------------------------------------------------------
__global__ __launch_bounds__(256) void gemm_proj_mfma(
    const u16* __restrict__ ctxb, const u16* __restrict__ wdt,
    const float* __restrict__ bd, const float* __restrict__ x,
    float* __restrict__ y)
{
    __shared__ u16 As[16384], Bs[16384];
    const int m0 = blockIdx.x * 128, n0 = blockIdx.y * 128;
    f32x4 acc[4][4];
#pragma unroll
    for (int i = 0; i < 4; ++i)
#pragma unroll
        for (int j = 0; j < 4; ++j) acc[i][j] = (f32x4){0.f, 0.f, 0.f, 0.f};

    gemm128_core<1>(ctxb, wdt, m0, n0, As, Bs, acc);

    const int lane = threadIdx.x & 63, wid = threadIdx.x >> 6;
    const int c16 = lane & 15, g = lane >> 4;
    const int wm = (wid >> 1) * 64, wn = (wid & 1) * 64;

#pragma unroll
    for (int mt = 0; mt < 4; ++mt) {
        int m = m0 + wm + mt * 16 + c16;
#pragma unroll
        for (int nt = 0; nt < 4; ++nt) {
            int nb = n0 + wn + nt * 16 + g * 4;
            float4 b4 = *(const float4*)&bd[nb];
            float4 x4 = *(const float4*)&x[(size_t)m * HIDc + nb];
            float4 o4;
            o4.x = acc[mt][nt][0] + b4.x + x4.x;
            o4.y = acc[mt][nt][1] + b4.y + x4.y;
            o4.z = acc[mt][nt][2] + b4.z + x4.z;
            o4.w = acc[mt][nt][3] + b4.w + x4.w;
            *(float4*)&y[(size_t)m * HIDc + nb] = o4;
        }
    }
}

// ---------------------------------------------------------------------------
// MFMA banded attention v5 (R10 known-good): 128 queries/block, 8 waves,
// 384-row LDS-staged window, per-wave 18-tile band, pm overlays kwin,
// two-phase PV. v6 (direct-global K/V, no staging) regressed 26->71us:
// load-on-demand MFMA operands are L2-latency-bound; bulk LDS prefetch wins.
// ---------------------------------------------------------------------------
__global__ __launch_bounds__(512) void band_attn_mfma(
    const u16* __restrict__ qg, const u16* __restrict__ kg,
    const u16* __restrict__ vtg, const u16* __restrict__ zpad,
    u16* __restrict__ ctxb)
{
    extern __shared__ u16 sm[];
    u16* kwin = sm;            // [384][64] (49152B), swizzle seg^(row&7)
    u16* vt   = sm + 24576;    // [64][384], swizzle (sl&~7)|((sl^d)&7)
    u16* pm   = sm;            // [128][192-stride] overlay on kwin

    const int L = blockIdx.x;              // 0..767
    const int xcd = L & 7, tt = L >> 3;    // tt 0..95
    const int hb = xcd * 3 + (tt % 3);     // 0..23
    const int qc = tt / 3;                 // 0..31
    const int h = hb % Hc, b = hb / Hc;

    const int s0 = qc * QT3;
    const int tid = threadIdx.x;
    const int lane = tid & 63, w = tid >> 6;
    const int c16 = lane & 15, g = lane >> 4;
    const size_t hbase = ((size_t)(b * Hc + h)) * Sc * Dc;

    const u16* qp = &qg[hbase + (size_t)(s0 + w * 16 + c16) * Dc + g * 8];
    bf16x8 qa0 = *(const bf16x8*)qp;
    bf16x8 qa1 = *(const bf16x8*)(qp + 32);

#pragma unroll
    for (int i = 0; i < 6; ++i) {
        int c   = i * 8 + w;
        int row = c * 8 + (lane >> 3);
        int seg = (lane & 7) ^ (lane >> 3);
        int pos = s0 - Wc + row;
        const u16* src = (pos >= 0 && pos < Sc)
                       ? &kg[hbase + (size_t)pos * Dc + seg * 8] : zpad;
        load_lds16(src, (char*)kwin + c * 1024 + (lane & 63) * 16);
    }
#pragma unroll
    for (int i = 0; i < 6; ++i) {
        int c   = i * 8 + w;
        int idx = c * 64 + lane;
        int d   = idx / 48;
        int p   = idx - d * 48;
        int seg = (p & ~7) | ((p ^ d) & 7);
        int pos0 = s0 - Wc + seg * 8;
        const u16* src = (pos0 >= 0 && pos0 < Sc)
                       ? &vtg[hbase + (size_t)d * Sc + pos0] : zpad;
        load_lds16(src, (char*)vt + idx * 16);
    }

    VM_BAR(6);   // Q + kwin landed everywhere; vt's 6 loads still in flight

    const int tb  = w & ~1;
    const int off = (w & 1) * 16;
    f32x4 acc[NCT3];
#pragma unroll
    for (int ct = 0; ct < NCT3; ++ct) acc[ct] = (f32x4){0.f, 0.f, 0.f, 0.f};
    __builtin_amdgcn_s_setprio(1);
#pragma unroll
    for (int ct = 0; ct < NCT3; ++ct) {
        int row = (tb + ct) * 16 + c16;
        const u16* kb = kwin + row * 64;
        bf16x8 kb0 = *(const bf16x8*)(kb + (g       ^ (row & 7)) * 8);
        bf16x8 kb1 = *(const bf16x8*)(kb + ((g + 4) ^ (row & 7)) * 8);
        acc[ct] = __builtin_amdgcn_mfma_f32_16x16x32_bf16(qa0, kb0, acc[ct], 0, 0, 0);
        acc[ct] = __builtin_amdgcn_mfma_f32_16x16x32_bf16(qa1, kb1, acc[ct], 0, 0, 0);
    }
    __builtin_amdgcn_s_setprio(0);

    float mrow[4] = {-3e38f, -3e38f, -3e38f, -3e38f};
#pragma unroll
    for (int ct = 0; ct < NCT3; ++ct) {
#pragma unroll
        for (int r = 0; r < 4; ++r) {
            int ql  = g * 4 + r;
            int jl  = ct * 16 + c16 - off;
            int pos = s0 - Wc + (tb + ct) * 16 + c16;
            bool valid = (jl >= ql) && (jl <= ql + 2 * Wc) && (pos >= 0) && (pos < Sc);
            float v = valid ? acc[ct][r] : -3e38f;
            acc[ct][r] = v;
            mrow[r] = fmaxf(mrow[r], v);
        }
    }
#pragma unroll
    for (int r = 0; r < 4; ++r)
#pragma unroll
        for (int o2 = 1; o2 < 16; o2 <<= 1)
            mrow[r] = fmaxf(mrow[r], __shfl_xor(mrow[r], o2));

    float srow[4] = {0.f, 0.f, 0.f, 0.f};
#pragma unroll
    for (int ct = 0; ct < NCT3; ++ct)
#pragma unroll
        for (int r = 0; r < 4; ++r) {
            float e = __expf(acc[ct][r] - mrow[r]);
            acc[ct][r] = e;
            srow[r] += e;
        }
#pragma unroll
    for (int r = 0; r < 4; ++r)
#pragma unroll
        for (int o2 = 1; o2 < 16; o2 <<= 1)
            srow[r] += __shfl_xor(srow[r], o2);

    VM_BAR(0);   // all waves done reading kwin; vt fully landed

    float sq0 = __shfl(srow[0], (c16 >> 2) << 4);
    float sq1 = __shfl(srow[1], (c16 >> 2) << 4);
    float sq2 = __shfl(srow[2], (c16 >> 2) << 4);
    float sq3 = __shfl(srow[3], (c16 >> 2) << 4);
    int rr = c16 & 3;
    float sq = rr == 0 ? sq0 : rr == 1 ? sq1 : rr == 2 ? sq2 : sq3;
    float invq = 1.f / sq;

    const int qrow = w * 16 + c16;
    f32x4 o[4];
#pragma unroll
    for (int dt = 0; dt < 4; ++dt) o[dt] = (f32x4){0.f, 0.f, 0.f, 0.f};

    // ======== PV phase A: tiles 0..9 ========
#pragma unroll
    for (int ct = 0; ct < 10; ++ct)
#pragma unroll
        for (int r = 0; r < 4; ++r) {
            int q   = w * 16 + g * 4 + r;
            int col = ct * 16 + c16;
            int sl  = col >> 3;
            int ph  = (sl & ~7) | ((sl ^ q ^ (q >> 3)) & 7);
            pm[q * 192 + ph * 8 + (col & 7)] = to_bf16(acc[ct][r]);
        }
    __builtin_amdgcn_s_setprio(1);
#pragma unroll
    for (int ks = 0; ks < 5; ++ks) {
        int sl = ks * 4 + g;
        int ph = (sl & ~7) | ((sl ^ qrow ^ (qrow >> 3)) & 7);
        bf16x8 pa = *(const bf16x8*)(pm + qrow * 192 + ph * 8);
#pragma unroll
        for (int dt = 0; dt < 4; ++dt) {
            int d  = dt * 16 + c16;
            int vs = tb * 2 + ks * 4 + g;
            int pv = (vs & ~7) | ((vs ^ d) & 7);
            bf16x8 vb = *(const bf16x8*)(vt + d * 384 + pv * 8);
            o[dt] = __builtin_amdgcn_mfma_f32_16x16x32_bf16(vb, pa, o[dt], 0, 0, 0);
        }
    }
    __builtin_amdgcn_s_setprio(0);

    // ======== PV phase B: tiles 10..17 ========
#pragma unroll
    for (int ct = 10; ct < NCT3; ++ct)
#pragma unroll
        for (int r = 0; r < 4; ++r) {
            int q   = w * 16 + g * 4 + r;
            int col = ct * 16 + c16 - 160;
            int sl  = col >> 3;
            int ph  = (sl & ~7) | ((sl ^ q ^ (q >> 3)) & 7);
            pm[q * 192 + ph * 8 + (col & 7)] = to_bf16(acc[ct][r]);
        }
    __builtin_amdgcn_s_setprio(1);
#pragma unroll
    for (int ks = 0; ks < 4; ++ks) {
        int sl = ks * 4 + g;
        int ph = (sl & ~7) | ((sl ^ qrow ^ (qrow >> 3)) & 7);
        bf16x8 pa = *(const bf16x8*)(pm + qrow * 192 + ph * 8);
#pragma unroll
        for (int dt = 0; dt < 4; ++dt) {
            int d  = dt * 16 + c16;
            int vs = tb * 2 + 20 + ks * 4 + g;
            int pv = (vs & ~7) | ((vs ^ d) & 7);
            bf16x8 vb = *(const bf16x8*)(vt + d * 384 + pv * 8);
            o[dt] = __builtin_amdgcn_mfma_f32_16x16x32_bf16(vb, pa, o[dt], 0, 0, 0);
        }
    }
    __builtin_amdgcn_s_setprio(0);

    const size_t crow = ((size_t)(b * Sc + s0 + qrow)) * HIDc + h * Dc;
#pragma unroll
    for (int dt = 0; dt < 4; ++dt) {
        ushort4 pk;
        pk.x = to_bf16(o[dt][0] * invq);
        pk.y = to_bf16(o[dt][1] * invq);
        pk.z = to_bf16(o[dt][2] * invq);
        pk.w = to_bf16(o[dt][3] * invq);
        *(ushort4*)&ctxb[crow + dt * 16 + g * 4] = pk;
    }
}

// ---------------------------------------------------------------------------
// LayerNorm over last dim (768), block per row
// ---------------------------------------------------------------------------
__global__ __launch_bounds__(256) void ln_kernel(
    const float* __restrict__ y,
    const float* __restrict__ gamma, const float* __restrict__ beta,
    float* __restrict__ out)
{
    const int m = blockIdx.x;
    const float* row = y + (size_t)m * HIDc;
    const int t = threadIdx.x;
    float v0 = row[t], v1 = row[t + 256], v2 = row[t + 512];
    float s = v0 + v1 + v2;
    __shared__ float red[4];
    const int lane = t & 63, wid = t >> 6;
#pragma unroll
    for (int o = 1; o < 64; o <<= 1) s += __shfl_xor(s, o);
    if (lane == 0) red[wid] = s;
    __syncthreads();
    const float mu = (red[0] + red[1] + red[2] + red[3]) * (1.f / HIDc);
    v0 -= mu; v1 -= mu; v2 -= mu;
    float s2 = v0 * v0 + v1 * v1 + v2 * v2;
#pragma unroll
    for (int o = 1; o < 64; o <<= 1) s2 += __shfl_xor(s2, o);
    __syncthreads();
    if (lane == 0) red[wid] = s2;
    __syncthreads();
    const float var = (red[0] + red[1] + red[2] + red[3]) * (1.f / HIDc);
    const float rstd = rsqrtf(var + 1e-12f);
    const size_t base = (size_t)m * HIDc;
    out[base + t]       = v0 * rstd * gamma[t]       + beta[t];
    out[base + t + 256] = v1 * rstd * gamma[t + 256] + beta[t + 256];
    out[base + t + 512] = v2 * rstd * gamma[t + 512] + beta[t + 512];
}

// ---------------------------------------------------------------------------
extern "C" void kernel_launch(void* const* d_in, const int* in_sizes, int n_in,
                              void* d_out, int out_size, void* d_ws, size_t ws_size,
                              hipStream_t stream)
{
    const float* x     = (const float*)d_in[0];
    const float* Wq    = (const float*)d_in[1];
    const float* bq    = (const float*)d_in[2];
    const float* Wk    = (const float*)d_in[3];
    const float* bk    = (const float*)d_in[4];
    const float* Wv    = (const float*)d_in[5];
    const float* bv    = (const float*)d_in[6];
    const float* Wd    = (const float*)d_in[7];
    const float* bd    = (const float*)d_in[8];
    const float* gamma = (const float*)d_in[9];
    const float* beta  = (const float*)d_in[10];
    float* out = (float*)d_out;

    constexpr size_t CHUNK = (size_t)Mc * HIDc;      // 6,291,456
    constexpr size_t WSZ   = (size_t)HIDc * HIDc;    //   589,824
    u16* xb   = (u16*)d_ws;
    u16* wqt  = xb + CHUNK;
    u16* wkt  = wqt + WSZ;
    u16* wvt  = wkt + WSZ;
    u16* wdt  = wvt + WSZ;
    u16* qg   = wdt + WSZ;
    u16* kg   = qg + CHUNK;
    u16* vtg  = kg + CHUNK;
    u16* ctxb = vtg + CHUNK;
    float* yws = (float*)(ctxb + CHUNK);
    u16* zpad  = (u16*)(yws + CHUNK);   // 2KB zero guard (filled by prep_all)

    // 0) fused precision prep (x->bf16, W->Wt bf16, zpad)
    prep_all<<<6144 + 2304, 256, 0, stream>>>(
        x, xb, zpad, Wq, Wk, Wv, Wd, wqt, wkt, wvt, wdt);

    // 1) merged QKV projections (R10 core: BK=64 dbuf, counted vmcnt)
    gemm_qkv_mfma<<<dim3(Mc / 128, HIDc / 128, 3), 256, 0, stream>>>(
        xb, wqt, wkt, wvt, bq, bk, bv, qg, kg, vtg);

    // 2) banded attention v5 (staged window, 96KB LDS)
    band_attn_mfma<<<dim3(Sc / QT3 * Hc * Bc), 512, 98304, stream>>>(
        qg, kg, vtg, zpad, ctxb);

    // 3) output projection + residual (R10 core)
    gemm_proj_mfma<<<dim3(Mc / 128, HIDc / 128), 256, 0, stream>>>(
        ctxb, wdt, bd, x, yws);

    // 4) LayerNorm
    ln_kernel<<<Mc, 256, 0, stream>>>(yws, gamma, beta, out);
}

// Round 16
// 120.978 us; speedup vs baseline: 1.3665x; 1.0212x over previous
//
#include <hip/hip_runtime.h>
#include <math.h>

typedef unsigned short u16;
typedef __bf16 bf16x8 __attribute__((ext_vector_type(8)));
typedef float f32x4 __attribute__((ext_vector_type(4)));

// Problem constants
constexpr int Bc   = 2;
constexpr int Sc   = 4096;
constexpr int HIDc = 768;
constexpr int Hc   = 12;
constexpr int Dc   = 64;
constexpr int Wc   = 128;
constexpr int Mc   = Bc * Sc;

// attention tiling (v5): 128 queries/block, 8 waves, per-wave 18-tile band
constexpr int QT3  = 128;
constexpr int NCT3 = 18;

#define VM_BAR(N) asm volatile("s_waitcnt vmcnt(" #N ")\n\ts_barrier" ::: "memory")
#define BAR()     asm volatile("s_barrier" ::: "memory")

static __device__ __forceinline__ void load_lds16(const void* g, void* l) {
    __builtin_amdgcn_global_load_lds(
        (const __attribute__((address_space(1))) void*)g,
        (__attribute__((address_space(3))) void*)l, 16, 0, 0);
}
static __device__ __forceinline__ u16 to_bf16(float f) {
    return __builtin_bit_cast(u16, (__bf16)f);
}
static __device__ __forceinline__ float from_bf16(u16 u) {
    return (float)__builtin_bit_cast(__bf16, u);
}

// ---------------------------------------------------------------------------
// Fused prep: blocks [0,6144): x fp32 -> bf16 (+ zpad fill in block 0);
// blocks [6144,8448): transpose W [K][N] fp32 -> Wt [N][K] bf16.
// ---------------------------------------------------------------------------
__global__ __launch_bounds__(256) void prep_all(
    const float* __restrict__ x, u16* __restrict__ xb, u16* __restrict__ zpad,
    const float* __restrict__ Wq, const float* __restrict__ Wk,
    const float* __restrict__ Wv, const float* __restrict__ Wd,
    u16* __restrict__ wqt, u16* __restrict__ wkt,
    u16* __restrict__ wvt, u16* __restrict__ wdt)
{
    const int bid = blockIdx.x;
    if (bid < 6144) {
        int i = bid * 256 + threadIdx.x;
        float4 v = ((const float4*)x)[i];
        ushort4 o;
        o.x = to_bf16(v.x); o.y = to_bf16(v.y);
        o.z = to_bf16(v.z); o.w = to_bf16(v.w);
        ((ushort4*)xb)[i] = o;
        if (bid == 0 && threadIdx.x < 128)
            ((int4*)zpad)[threadIdx.x] = make_int4(0, 0, 0, 0);  // 2KB zeros
    } else {
        int r = bid - 6144;                 // 0..2303
        int z = r / 576, xy = r - z * 576;  // 576 = 24*24 tiles per matrix
        const float* W = z == 0 ? Wq : z == 1 ? Wk : z == 2 ? Wv : Wd;
        u16* T         = z == 0 ? wqt : z == 1 ? wkt : z == 2 ? wvt : wdt;
        __shared__ float t[32][33];
        const int bx = (xy % 24) * 32, by = (xy / 24) * 32;
        const int tx = threadIdx.x & 31, ty = threadIdx.x >> 5;
#pragma unroll
        for (int i = 0; i < 32; i += 8)
            t[ty + i][tx] = W[(size_t)(by + ty + i) * HIDc + bx + tx];
        __syncthreads();
#pragma unroll
        for (int i = 0; i < 32; i += 8)
            T[(size_t)(bx + ty + i) * HIDc + by + tx] = to_bf16(t[tx][ty + i]);
    }
}

// ---------------------------------------------------------------------------
// BK=64 tile pair stager (R10 known-good): 128 rows x 64 k each for A, B^T.
// Row = 128B = 8 x 16B slots; swizzle slot8 = phys ^ (row&7).
// 8 global_load_lds per wave (4 A + 4 B) -> vmcnt unit = 8.
// ---------------------------------------------------------------------------
__device__ __forceinline__ void stage64(const u16* __restrict__ A,
                                        const u16* __restrict__ Bt,
                                        int m0, int n0, int k0,
                                        u16* As, u16* Bs, int soff)
{
#pragma unroll
    for (int i = 0; i < 4; ++i) {
        int off  = soff + i * 1024;
        int row  = off >> 7;
        int slot = (off >> 4) & 7;
        int seg  = slot ^ (row & 7);
        load_lds16(A  + (size_t)(m0 + row) * HIDc + k0 + seg * 8, (char*)As + off);
        load_lds16(Bt + (size_t)(n0 + row) * HIDc + k0 + seg * 8, (char*)Bs + off);
    }
}

// ---------------------------------------------------------------------------
// 128x128 B^T MFMA GEMM core, K=768, BK=64, double-buffered (64KB LDS) with
// COUNTED vmcnt: per iter {STAGE(t+1); vmcnt(8)+bar; ds_read+MFMA(t); bar}.
// Empirical local optimum: BK32-drain (R5), BK32-counted (R9), 256x128
// 3-stage ring (R11), B-direct (R12) all regressed. 3-buf single-barrier
// needs 96KB -> 1 blk/CU (R11 trap) — blocked.
// SWAP=0: acc row=m, col=n.  SWAP=1: operands swapped -> row=n, col=m.
// ---------------------------------------------------------------------------
template <int SWAP>
__device__ __forceinline__ void gemm128_core(
    const u16* __restrict__ A, const u16* __restrict__ Bt,
    int m0, int n0, u16* As, u16* Bs, f32x4 (&acc)[4][4])
{
    const int lane = threadIdx.x & 63, wid = threadIdx.x >> 6;
    const int c16 = lane & 15, g = lane >> 4;
    const int wm = (wid >> 1) * 64, wn = (wid & 1) * 64;
    const int soff = wid * 4096 + lane * 16;

    stage64(A, Bt, m0, n0, 0, As, Bs, soff);
    int cur = 0;
    for (int t = 0; t < 12; ++t) {
        if (t < 11) {
            stage64(A, Bt, m0, n0, (t + 1) * 64,
                    As + (cur ^ 1) * 8192, Bs + (cur ^ 1) * 8192, soff);
            VM_BAR(8);          // stage(t) landed; stage(t+1) in flight
        } else {
            VM_BAR(0);
        }
        const u16* Ab = As + cur * 8192;
        const u16* Bb = Bs + cur * 8192;
#pragma unroll
        for (int kk = 0; kk < 2; ++kk) {
            bf16x8 af[4], bfr[4];
#pragma unroll
            for (int tt = 0; tt < 4; ++tt) {
                int ar = wm + tt * 16 + c16;
                int a8 = (kk * 4 + g) ^ (ar & 7);
                af[tt] = *(const bf16x8*)(Ab + ar * 64 + a8 * 8);
                int br = wn + tt * 16 + c16;
                int b8 = (kk * 4 + g) ^ (br & 7);
                bfr[tt] = *(const bf16x8*)(Bb + br * 64 + b8 * 8);
            }
            __builtin_amdgcn_s_setprio(1);
#pragma unroll
            for (int mt = 0; mt < 4; ++mt)
#pragma unroll
                for (int nt = 0; nt < 4; ++nt)
                    acc[mt][nt] = SWAP
                        ? __builtin_amdgcn_mfma_f32_16x16x32_bf16(
                              bfr[nt], af[mt], acc[mt][nt], 0, 0, 0)
                        : __builtin_amdgcn_mfma_f32_16x16x32_bf16(
                              af[mt], bfr[nt], acc[mt][nt], 0, 0, 0);
            __builtin_amdgcn_s_setprio(0);
        }
        BAR();
        cur ^= 1;
    }
}

// ---------------------------------------------------------------------------
// Merged QKV projection (z=0..2, 1152 blocks; R10 known-good).
// z=0/1 (Q,K): SWAP=1 -> ushort4 store into [B,H,S,D] (Q scaled 1/8).
// z=2   (V) : SWAP=0 -> ushort4 store into transposed [B,H,D,S].
// ---------------------------------------------------------------------------
__global__ __launch_bounds__(256) void gemm_qkv_mfma(
    const u16* __restrict__ xb,
    const u16* __restrict__ wqt, const u16* __restrict__ wkt,
    const u16* __restrict__ wvt,
    const float* __restrict__ bq, const float* __restrict__ bk,
    const float* __restrict__ bv,
    u16* __restrict__ qg, u16* __restrict__ kg, u16* __restrict__ vtg)
{
    __shared__ u16 As[16384], Bs[16384];
    const int z = blockIdx.z;
    const u16* Bt     = z == 0 ? wqt : z == 1 ? wkt : wvt;
    const float* bias = z == 0 ? bq : z == 1 ? bk : bv;

    const int m0 = blockIdx.x * 128, n0 = blockIdx.y * 128;
    f32x4 acc[4][4];
#pragma unroll
    for (int i = 0; i < 4; ++i)
#pragma unroll
        for (int j = 0; j < 4; ++j) acc[i][j] = (f32x4){0.f, 0.f, 0.f, 0.f};

    const int lane = threadIdx.x & 63, wid = threadIdx.x >> 6;
    const int c16 = lane & 15, g = lane >> 4;
    const int wm = (wid >> 1) * 64, wn = (wid & 1) * 64;

    if (z == 2) {
        gemm128_core<0>(xb, Bt, m0, n0, As, Bs, acc);
#pragma unroll
        for (int nt = 0; nt < 4; ++nt) {
            int n = n0 + wn + nt * 16 + c16;
            int h = n >> 6, d = n & 63;
            float bn = bias[n];
#pragma unroll
            for (int mt = 0; mt < 4; ++mt) {
                int m = m0 + wm + mt * 16 + g * 4;
                int b = m >> 12, s = m & (Sc - 1);
                size_t base = ((size_t)(b * Hc + h)) * Sc * Dc + (size_t)d * Sc + s;
                ushort4 pk;
                pk.x = to_bf16(acc[mt][nt][0] + bn);
                pk.y = to_bf16(acc[mt][nt][1] + bn);
                pk.z = to_bf16(acc[mt][nt][2] + bn);
                pk.w = to_bf16(acc[mt][nt][3] + bn);
                *(ushort4*)&vtg[base] = pk;
            }
        }
    } else {
        gemm128_core<1>(xb, Bt, m0, n0, As, Bs, acc);
        const float scale = z ? 1.0f : 0.125f;
        u16* outp = z ? kg : qg;
#pragma unroll
        for (int mt = 0; mt < 4; ++mt) {
            int m = m0 + wm + mt * 16 + c16;
            int b = m >> 12, s = m & (Sc - 1);
            size_t rowbase = (size_t)(b * Hc) * Sc * Dc + (size_t)s * Dc;
#pragma unroll
            for (int nt = 0; nt < 4; ++nt) {
                int nb = n0 + wn + nt * 16 + g * 4;
                int h = nb >> 6, d0 = nb & 63;
                float4 b4 = *(const float4*)&bias[nb];
                ushort4 pk;
                pk.x = to_bf16((acc[mt][nt][0] + b4.x) * scale);
                pk.y = to_bf16((acc[mt][nt][1] + b4.y) * scale);
                pk.z = to_bf16((acc[mt][nt][2] + b4.z) * scale);
                pk.w = to_bf16((acc[mt][nt][3] + b4.w) * scale);
                *(ushort4*)&outp[rowbase + (size_t)h * Sc * Dc + d0] = pk;
            }
        }
    }
}

// ---------------------------------------------------------------------------
// Output projection + residual (SWAP=1, R10 core). NEW: y stored as bf16
// (halves proj write + ln read traffic; adds ~0.004 abs error, margin 3x).
// ---------------------------------------------------------------------------
__global__ __launch_bounds__(256) void gemm_proj_mfma(
    const u16* __restrict__ ctxb, const u16* __restrict__ wdt,
    const float* __restrict__ bd, const float* __restrict__ x,
    u16* __restrict__ yb)
{
    __shared__ u16 As[16384], Bs[16384];
    const int m0 = blockIdx.x * 128, n0 = blockIdx.y * 128;
    f32x4 acc[4][4];
#pragma unroll
    for (int i = 0; i < 4; ++i)
#pragma unroll
        for (int j = 0; j < 4; ++j) acc[i][j] = (f32x4){0.f, 0.f, 0.f, 0.f};

    gemm128_core<1>(ctxb, wdt, m0, n0, As, Bs, acc);

    const int lane = threadIdx.x & 63, wid = threadIdx.x >> 6;
    const int c16 = lane & 15, g = lane >> 4;
    const int wm = (wid >> 1) * 64, wn = (wid & 1) * 64;

#pragma unroll
    for (int mt = 0; mt < 4; ++mt) {
        int m = m0 + wm + mt * 16 + c16;
#pragma unroll
        for (int nt = 0; nt < 4; ++nt) {
            int nb = n0 + wn + nt * 16 + g * 4;
            float4 b4 = *(const float4*)&bd[nb];
            float4 x4 = *(const float4*)&x[(size_t)m * HIDc + nb];
            ushort4 pk;
            pk.x = to_bf16(acc[mt][nt][0] + b4.x + x4.x);
            pk.y = to_bf16(acc[mt][nt][1] + b4.y + x4.y);
            pk.z = to_bf16(acc[mt][nt][2] + b4.z + x4.z);
            pk.w = to_bf16(acc[mt][nt][3] + b4.w + x4.w);
            *(ushort4*)&yb[(size_t)m * HIDc + nb] = pk;
        }
    }
}

// ---------------------------------------------------------------------------
// MFMA banded attention v5 (R10 known-good): 128 queries/block, 8 waves,
// 384-row LDS-staged window, per-wave 18-tile band, pm overlays kwin,
// two-phase PV. (v6 direct-global K/V regressed 26->71us: load-on-demand
// MFMA operands are L2-latency-bound; bulk LDS prefetch wins.)
// ---------------------------------------------------------------------------
__global__ __launch_bounds__(512) void band_attn_mfma(
    const u16* __restrict__ qg, const u16* __restrict__ kg,
    const u16* __restrict__ vtg, const u16* __restrict__ zpad,
    u16* __restrict__ ctxb)
{
    extern __shared__ u16 sm[];
    u16* kwin = sm;            // [384][64] (49152B), swizzle seg^(row&7)
    u16* vt   = sm + 24576;    // [64][384], swizzle (sl&~7)|((sl^d)&7)
    u16* pm   = sm;            // [128][192-stride] overlay on kwin

    const int L = blockIdx.x;              // 0..767
    const int xcd = L & 7, tt = L >> 3;    // tt 0..95
    const int hb = xcd * 3 + (tt % 3);     // 0..23
    const int qc = tt / 3;                 // 0..31
    const int h = hb % Hc, b = hb / Hc;

    const int s0 = qc * QT3;
    const int tid = threadIdx.x;
    const int lane = tid & 63, w = tid >> 6;
    const int c16 = lane & 15, g = lane >> 4;
    const size_t hbase = ((size_t)(b * Hc + h)) * Sc * Dc;

    const u16* qp = &qg[hbase + (size_t)(s0 + w * 16 + c16) * Dc + g * 8];
    bf16x8 qa0 = *(const bf16x8*)qp;
    bf16x8 qa1 = *(const bf16x8*)(qp + 32);

#pragma unroll
    for (int i = 0; i < 6; ++i) {
        int c   = i * 8 + w;
        int row = c * 8 + (lane >> 3);
        int seg = (lane & 7) ^ (lane >> 3);
        int pos = s0 - Wc + row;
        const u16* src = (pos >= 0 && pos < Sc)
                       ? &kg[hbase + (size_t)pos * Dc + seg * 8] : zpad;
        load_lds16(src, (char*)kwin + c * 1024 + (lane & 63) * 16);
    }
#pragma unroll
    for (int i = 0; i < 6; ++i) {
        int c   = i * 8 + w;
        int idx = c * 64 + lane;
        int d   = idx / 48;
        int p   = idx - d * 48;
        int seg = (p & ~7) | ((p ^ d) & 7);
        int pos0 = s0 - Wc + seg * 8;
        const u16* src = (pos0 >= 0 && pos0 < Sc)
                       ? &vtg[hbase + (size_t)d * Sc + pos0] : zpad;
        load_lds16(src, (char*)vt + idx * 16);
    }

    VM_BAR(6);   // Q + kwin landed everywhere; vt's 6 loads still in flight

    const int tb  = w & ~1;
    const int off = (w & 1) * 16;
    f32x4 acc[NCT3];
#pragma unroll
    for (int ct = 0; ct < NCT3; ++ct) acc[ct] = (f32x4){0.f, 0.f, 0.f, 0.f};
    __builtin_amdgcn_s_setprio(1);
#pragma unroll
    for (int ct = 0; ct < NCT3; ++ct) {
        int row = (tb + ct) * 16 + c16;
        const u16* kb = kwin + row * 64;
        bf16x8 kb0 = *(const bf16x8*)(kb + (g       ^ (row & 7)) * 8);
        bf16x8 kb1 = *(const bf16x8*)(kb + ((g + 4) ^ (row & 7)) * 8);
        acc[ct] = __builtin_amdgcn_mfma_f32_16x16x32_bf16(qa0, kb0, acc[ct], 0, 0, 0);
        acc[ct] = __builtin_amdgcn_mfma_f32_16x16x32_bf16(qa1, kb1, acc[ct], 0, 0, 0);
    }
    __builtin_amdgcn_s_setprio(0);

    float mrow[4] = {-3e38f, -3e38f, -3e38f, -3e38f};
#pragma unroll
    for (int ct = 0; ct < NCT3; ++ct) {
#pragma unroll
        for (int r = 0; r < 4; ++r) {
            int ql  = g * 4 + r;
            int jl  = ct * 16 + c16 - off;
            int pos = s0 - Wc + (tb + ct) * 16 + c16;
            bool valid = (jl >= ql) && (jl <= ql + 2 * Wc) && (pos >= 0) && (pos < Sc);
            float v = valid ? acc[ct][r] : -3e38f;
            acc[ct][r] = v;
            mrow[r] = fmaxf(mrow[r], v);
        }
    }
#pragma unroll
    for (int r = 0; r < 4; ++r)
#pragma unroll
        for (int o2 = 1; o2 < 16; o2 <<= 1)
            mrow[r] = fmaxf(mrow[r], __shfl_xor(mrow[r], o2));

    float srow[4] = {0.f, 0.f, 0.f, 0.f};
#pragma unroll
    for (int ct = 0; ct < NCT3; ++ct)
#pragma unroll
        for (int r = 0; r < 4; ++r) {
            float e = __expf(acc[ct][r] - mrow[r]);
            acc[ct][r] = e;
            srow[r] += e;
        }
#pragma unroll
    for (int r = 0; r < 4; ++r)
#pragma unroll
        for (int o2 = 1; o2 < 16; o2 <<= 1)
            srow[r] += __shfl_xor(srow[r], o2);

    VM_BAR(0);   // all waves done reading kwin; vt fully landed

    float sq0 = __shfl(srow[0], (c16 >> 2) << 4);
    float sq1 = __shfl(srow[1], (c16 >> 2) << 4);
    float sq2 = __shfl(srow[2], (c16 >> 2) << 4);
    float sq3 = __shfl(srow[3], (c16 >> 2) << 4);
    int rr = c16 & 3;
    float sq = rr == 0 ? sq0 : rr == 1 ? sq1 : rr == 2 ? sq2 : sq3;
    float invq = 1.f / sq;

    const int qrow = w * 16 + c16;
    f32x4 o[4];
#pragma unroll
    for (int dt = 0; dt < 4; ++dt) o[dt] = (f32x4){0.f, 0.f, 0.f, 0.f};

    // ======== PV phase A: tiles 0..9 ========
#pragma unroll
    for (int ct = 0; ct < 10; ++ct)
#pragma unroll
        for (int r = 0; r < 4; ++r) {
            int q   = w * 16 + g * 4 + r;
            int col = ct * 16 + c16;
            int sl  = col >> 3;
            int ph  = (sl & ~7) | ((sl ^ q ^ (q >> 3)) & 7);
            pm[q * 192 + ph * 8 + (col & 7)] = to_bf16(acc[ct][r]);
        }
    __builtin_amdgcn_s_setprio(1);
#pragma unroll
    for (int ks = 0; ks < 5; ++ks) {
        int sl = ks * 4 + g;
        int ph = (sl & ~7) | ((sl ^ qrow ^ (qrow >> 3)) & 7);
        bf16x8 pa = *(const bf16x8*)(pm + qrow * 192 + ph * 8);
#pragma unroll
        for (int dt = 0; dt < 4; ++dt) {
            int d  = dt * 16 + c16;
            int vs = tb * 2 + ks * 4 + g;
            int pv = (vs & ~7) | ((vs ^ d) & 7);
            bf16x8 vb = *(const bf16x8*)(vt + d * 384 + pv * 8);
            o[dt] = __builtin_amdgcn_mfma_f32_16x16x32_bf16(vb, pa, o[dt], 0, 0, 0);
        }
    }
    __builtin_amdgcn_s_setprio(0);

    // ======== PV phase B: tiles 10..17 ========
#pragma unroll
    for (int ct = 10; ct < NCT3; ++ct)
#pragma unroll
        for (int r = 0; r < 4; ++r) {
            int q   = w * 16 + g * 4 + r;
            int col = ct * 16 + c16 - 160;
            int sl  = col >> 3;
            int ph  = (sl & ~7) | ((sl ^ q ^ (q >> 3)) & 7);
            pm[q * 192 + ph * 8 + (col & 7)] = to_bf16(acc[ct][r]);
        }
    __builtin_amdgcn_s_setprio(1);
#pragma unroll
    for (int ks = 0; ks < 4; ++ks) {
        int sl = ks * 4 + g;
        int ph = (sl & ~7) | ((sl ^ qrow ^ (qrow >> 3)) & 7);
        bf16x8 pa = *(const bf16x8*)(pm + qrow * 192 + ph * 8);
#pragma unroll
        for (int dt = 0; dt < 4; ++dt) {
            int d  = dt * 16 + c16;
            int vs = tb * 2 + 20 + ks * 4 + g;
            int pv = (vs & ~7) | ((vs ^ d) & 7);
            bf16x8 vb = *(const bf16x8*)(vt + d * 384 + pv * 8);
            o[dt] = __builtin_amdgcn_mfma_f32_16x16x32_bf16(vb, pa, o[dt], 0, 0, 0);
        }
    }
    __builtin_amdgcn_s_setprio(0);

    const size_t crow = ((size_t)(b * Sc + s0 + qrow)) * HIDc + h * Dc;
#pragma unroll
    for (int dt = 0; dt < 4; ++dt) {
        ushort4 pk;
        pk.x = to_bf16(o[dt][0] * invq);
        pk.y = to_bf16(o[dt][1] * invq);
        pk.z = to_bf16(o[dt][2] * invq);
        pk.w = to_bf16(o[dt][3] * invq);
        *(ushort4*)&ctxb[crow + dt * 16 + g * 4] = pk;
    }
}

// ---------------------------------------------------------------------------
// LayerNorm v2: y is bf16. 8192 blocks x 192 threads (3 waves); each thread
// loads one ushort4 (row = 192 coalesced ushort4 = 1536B), fp32 math,
// fp32 out. Vectorized bf16 loads per G13.
// ---------------------------------------------------------------------------
__global__ __launch_bounds__(192) void ln_kernel(
    const u16* __restrict__ yb,
    const float* __restrict__ gamma, const float* __restrict__ beta,
    float* __restrict__ out)
{
    const int m = blockIdx.x;
    const int t = threadIdx.x;
    const int lane = t & 63, wid = t >> 6;

    ushort4 v4 = *(const ushort4*)&yb[(size_t)m * HIDc + t * 4];
    float v0 = from_bf16(v4.x), v1 = from_bf16(v4.y);
    float v2 = from_bf16(v4.z), v3 = from_bf16(v4.w);

    __shared__ float red[3];
    float s = v0 + v1 + v2 + v3;
#pragma unroll
    for (int o = 1; o < 64; o <<= 1) s += __shfl_xor(s, o);
    if (lane == 0) red[wid] = s;
    __syncthreads();
    const float mu = (red[0] + red[1] + red[2]) * (1.f / HIDc);
    v0 -= mu; v1 -= mu; v2 -= mu; v3 -= mu;
    float s2 = v0 * v0 + v1 * v1 + v2 * v2 + v3 * v3;
#pragma unroll
    for (int o = 1; o < 64; o <<= 1) s2 += __shfl_xor(s2, o);
    __syncthreads();
    if (lane == 0) red[wid] = s2;
    __syncthreads();
    const float var = (red[0] + red[1] + red[2]) * (1.f / HIDc);
    const float rstd = rsqrtf(var + 1e-12f);

    float4 g4 = *(const float4*)&gamma[t * 4];
    float4 b4 = *(const float4*)&beta[t * 4];
    float4 o4;
    o4.x = v0 * rstd * g4.x + b4.x;
    o4.y = v1 * rstd * g4.y + b4.y;
    o4.z = v2 * rstd * g4.z + b4.z;
    o4.w = v3 * rstd * g4.w + b4.w;
    *(float4*)&out[(size_t)m * HIDc + t * 4] = o4;
}

// ---------------------------------------------------------------------------
extern "C" void kernel_launch(void* const* d_in, const int* in_sizes, int n_in,
                              void* d_out, int out_size, void* d_ws, size_t ws_size,
                              hipStream_t stream)
{
    const float* x     = (const float*)d_in[0];
    const float* Wq    = (const float*)d_in[1];
    const float* bq    = (const float*)d_in[2];
    const float* Wk    = (const float*)d_in[3];
    const float* bk    = (const float*)d_in[4];
    const float* Wv    = (const float*)d_in[5];
    const float* bv    = (const float*)d_in[6];
    const float* Wd    = (const float*)d_in[7];
    const float* bd    = (const float*)d_in[8];
    const float* gamma = (const float*)d_in[9];
    const float* beta  = (const float*)d_in[10];
    float* out = (float*)d_out;

    constexpr size_t CHUNK = (size_t)Mc * HIDc;      // 6,291,456
    constexpr size_t WSZ   = (size_t)HIDc * HIDc;    //   589,824
    u16* xb   = (u16*)d_ws;
    u16* wqt  = xb + CHUNK;
    u16* wkt  = wqt + WSZ;
    u16* wvt  = wkt + WSZ;
    u16* wdt  = wvt + WSZ;
    u16* qg   = wdt + WSZ;
    u16* kg   = qg + CHUNK;
    u16* vtg  = kg + CHUNK;
    u16* ctxb = vtg + CHUNK;
    u16* yb   = ctxb + CHUNK;           // bf16 y (pre-LN)
    u16* zpad = yb + CHUNK;             // 2KB zero guard (filled by prep_all)

    // 0) fused precision prep (x->bf16, W->Wt bf16, zpad)
    prep_all<<<6144 + 2304, 256, 0, stream>>>(
        x, xb, zpad, Wq, Wk, Wv, Wd, wqt, wkt, wvt, wdt);

    // 1) merged QKV projections (R10 core: BK=64 dbuf, counted vmcnt)
    gemm_qkv_mfma<<<dim3(Mc / 128, HIDc / 128, 3), 256, 0, stream>>>(
        xb, wqt, wkt, wvt, bq, bk, bv, qg, kg, vtg);

    // 2) banded attention v5 (staged window, 96KB LDS)
    band_attn_mfma<<<dim3(Sc / QT3 * Hc * Bc), 512, 98304, stream>>>(
        qg, kg, vtg, zpad, ctxb);

    // 3) output projection + residual (R10 core, bf16 y out)
    gemm_proj_mfma<<<dim3(Mc / 128, HIDc / 128), 256, 0, stream>>>(
        ctxb, wdt, bd, x, yb);

    // 4) LayerNorm (bf16 in, fp32 out)
    ln_kernel<<<Mc, 192, 0, stream>>>(yb, gamma, beta, out);
}

// Round 17
// 120.416 us; speedup vs baseline: 1.3729x; 1.0047x over previous
//
#include <hip/hip_runtime.h>
#include <math.h>

typedef unsigned short u16;
typedef __bf16 bf16x8 __attribute__((ext_vector_type(8)));
typedef float f32x4 __attribute__((ext_vector_type(4)));

// Problem constants
constexpr int Bc   = 2;
constexpr int Sc   = 4096;
constexpr int HIDc = 768;
constexpr int Hc   = 12;
constexpr int Dc   = 64;
constexpr int Wc   = 128;
constexpr int Mc   = Bc * Sc;

// attention tiling (v5): 128 queries/block, 8 waves, per-wave 18-tile band
constexpr int QT3  = 128;
constexpr int NCT3 = 18;

#define VM_BAR(N) asm volatile("s_waitcnt vmcnt(" #N ")\n\ts_barrier" ::: "memory")
#define BAR()     asm volatile("s_barrier" ::: "memory")

static __device__ __forceinline__ void load_lds16(const void* g, void* l) {
    __builtin_amdgcn_global_load_lds(
        (const __attribute__((address_space(1))) void*)g,
        (__attribute__((address_space(3))) void*)l, 16, 0, 0);
}
static __device__ __forceinline__ u16 to_bf16(float f) {
    return __builtin_bit_cast(u16, (__bf16)f);
}
static __device__ __forceinline__ float from_bf16(u16 u) {
    return (float)__builtin_bit_cast(__bf16, u);
}

// ---------------------------------------------------------------------------
// Fused prep: blocks [0,6144): x fp32 -> bf16 (+ zpad fill in block 0);
// blocks [6144,8448): transpose W [K][N] fp32 -> Wt [N][K] bf16.
// ---------------------------------------------------------------------------
__global__ __launch_bounds__(256) void prep_all(
    const float* __restrict__ x, u16* __restrict__ xb, u16* __restrict__ zpad,
    const float* __restrict__ Wq, const float* __restrict__ Wk,
    const float* __restrict__ Wv, const float* __restrict__ Wd,
    u16* __restrict__ wqt, u16* __restrict__ wkt,
    u16* __restrict__ wvt, u16* __restrict__ wdt)
{
    const int bid = blockIdx.x;
    if (bid < 6144) {
        int i = bid * 256 + threadIdx.x;
        float4 v = ((const float4*)x)[i];
        ushort4 o;
        o.x = to_bf16(v.x); o.y = to_bf16(v.y);
        o.z = to_bf16(v.z); o.w = to_bf16(v.w);
        ((ushort4*)xb)[i] = o;
        if (bid == 0 && threadIdx.x < 128)
            ((int4*)zpad)[threadIdx.x] = make_int4(0, 0, 0, 0);  // 2KB zeros
    } else {
        int r = bid - 6144;                 // 0..2303
        int z = r / 576, xy = r - z * 576;  // 576 = 24*24 tiles per matrix
        const float* W = z == 0 ? Wq : z == 1 ? Wk : z == 2 ? Wv : Wd;
        u16* T         = z == 0 ? wqt : z == 1 ? wkt : z == 2 ? wvt : wdt;
        __shared__ float t[32][33];
        const int bx = (xy % 24) * 32, by = (xy / 24) * 32;
        const int tx = threadIdx.x & 31, ty = threadIdx.x >> 5;
#pragma unroll
        for (int i = 0; i < 32; i += 8)
            t[ty + i][tx] = W[(size_t)(by + ty + i) * HIDc + bx + tx];
        __syncthreads();
#pragma unroll
        for (int i = 0; i < 32; i += 8)
            T[(size_t)(bx + ty + i) * HIDc + by + tx] = to_bf16(t[tx][ty + i]);
    }
}

// ---------------------------------------------------------------------------
// BK=64 tile pair stager (R10 known-good): 128 rows x 64 k each for A, B^T.
// Row = 128B = 8 x 16B slots; swizzle slot8 = phys ^ (row&7).
// 8 global_load_lds per wave (4 A + 4 B) -> vmcnt unit = 8.
// ---------------------------------------------------------------------------
__device__ __forceinline__ void stage64(const u16* __restrict__ A,
                                        const u16* __restrict__ Bt,
                                        int m0, int n0, int k0,
                                        u16* As, u16* Bs, int soff)
{
#pragma unroll
    for (int i = 0; i < 4; ++i) {
        int off  = soff + i * 1024;
        int row  = off >> 7;
        int slot = (off >> 4) & 7;
        int seg  = slot ^ (row & 7);
        load_lds16(A  + (size_t)(m0 + row) * HIDc + k0 + seg * 8, (char*)As + off);
        load_lds16(Bt + (size_t)(n0 + row) * HIDc + k0 + seg * 8, (char*)Bs + off);
    }
}

// ---------------------------------------------------------------------------
// 128x128 B^T MFMA GEMM core, K=768, BK=64, double-buffered (64KB LDS) with
// COUNTED vmcnt: per iter {STAGE(t+1); vmcnt(8)+bar; ds_read+MFMA(t); bar}.
// Empirical local optimum for this K=768 family (R5/R9/R11/R12 variants all
// regressed). Latency-sensitive: VM_BAR(8) waits ~[load-latency - 1 iter],
// so L2-resident stage sources (XCD swizzle) shorten the critical path.
// SWAP=0: acc row=m, col=n.  SWAP=1: operands swapped -> row=n, col=m.
// ---------------------------------------------------------------------------
template <int SWAP>
__device__ __forceinline__ void gemm128_core(
    const u16* __restrict__ A, const u16* __restrict__ Bt,
    int m0, int n0, u16* As, u16* Bs, f32x4 (&acc)[4][4])
{
    const int lane = threadIdx.x & 63, wid = threadIdx.x >> 6;
    const int c16 = lane & 15, g = lane >> 4;
    const int wm = (wid >> 1) * 64, wn = (wid & 1) * 64;
    const int soff = wid * 4096 + lane * 16;

    stage64(A, Bt, m0, n0, 0, As, Bs, soff);
    int cur = 0;
    for (int t = 0; t < 12; ++t) {
        if (t < 11) {
            stage64(A, Bt, m0, n0, (t + 1) * 64,
                    As + (cur ^ 1) * 8192, Bs + (cur ^ 1) * 8192, soff);
            VM_BAR(8);          // stage(t) landed; stage(t+1) in flight
        } else {
            VM_BAR(0);
        }
        const u16* Ab = As + cur * 8192;
        const u16* Bb = Bs + cur * 8192;
#pragma unroll
        for (int kk = 0; kk < 2; ++kk) {
            bf16x8 af[4], bfr[4];
#pragma unroll
            for (int tt = 0; tt < 4; ++tt) {
                int ar = wm + tt * 16 + c16;
                int a8 = (kk * 4 + g) ^ (ar & 7);
                af[tt] = *(const bf16x8*)(Ab + ar * 64 + a8 * 8);
                int br = wn + tt * 16 + c16;
                int b8 = (kk * 4 + g) ^ (br & 7);
                bfr[tt] = *(const bf16x8*)(Bb + br * 64 + b8 * 8);
            }
            __builtin_amdgcn_s_setprio(1);
#pragma unroll
            for (int mt = 0; mt < 4; ++mt)
#pragma unroll
                for (int nt = 0; nt < 4; ++nt)
                    acc[mt][nt] = SWAP
                        ? __builtin_amdgcn_mfma_f32_16x16x32_bf16(
                              bfr[nt], af[mt], acc[mt][nt], 0, 0, 0)
                        : __builtin_amdgcn_mfma_f32_16x16x32_bf16(
                              af[mt], bfr[nt], acc[mt][nt], 0, 0, 0);
            __builtin_amdgcn_s_setprio(0);
        }
        BAR();
        cur ^= 1;
    }
}

// ---------------------------------------------------------------------------
// Merged QKV projection. NEW: 1D grid (1152 blocks) with XCD-aware decode —
// xcd = wgid&7 owns m-tiles [xcd*8, xcd*8+8) x all 18 (n,z): per-XCD A-slice
// 1.57MB + concurrent B panels ~1.5MB both L2-resident (4MB/XCD), shortening
// the counted-vmcnt stage waits. Bijective (1152 % 8 == 0).
// z=0/1 (Q,K): SWAP=1 -> ushort4 store into [B,H,S,D] (Q scaled 1/8).
// z=2   (V) : SWAP=0 -> ushort4 store into transposed [B,H,D,S].
// ---------------------------------------------------------------------------
__global__ __launch_bounds__(256) void gemm_qkv_mfma(
    const u16* __restrict__ xb,
    const u16* __restrict__ wqt, const u16* __restrict__ wkt,
    const u16* __restrict__ wvt,
    const float* __restrict__ bq, const float* __restrict__ bk,
    const float* __restrict__ bv,
    u16* __restrict__ qg, u16* __restrict__ kg, u16* __restrict__ vtg)
{
    __shared__ u16 As[16384], Bs[16384];

    // XCD-clustered decode
    const int wgid = blockIdx.x;
    const int xcd  = wgid & 7;
    const int j    = wgid >> 3;          // 0..143
    const int mt_  = xcd * 8 + (j & 7);  // m-tile 0..63 (XCD-local range)
    const int rest = j >> 3;             // 0..17
    const int nt_  = rest % 6;
    const int z    = rest / 6;

    const u16* Bt     = z == 0 ? wqt : z == 1 ? wkt : wvt;
    const float* bias = z == 0 ? bq : z == 1 ? bk : bv;

    const int m0 = mt_ * 128, n0 = nt_ * 128;
    f32x4 acc[4][4];
#pragma unroll
    for (int i = 0; i < 4; ++i)
#pragma unroll
        for (int j2 = 0; j2 < 4; ++j2) acc[i][j2] = (f32x4){0.f, 0.f, 0.f, 0.f};

    const int lane = threadIdx.x & 63, wid = threadIdx.x >> 6;
    const int c16 = lane & 15, g = lane >> 4;
    const int wm = (wid >> 1) * 64, wn = (wid & 1) * 64;

    if (z == 2) {
        gemm128_core<0>(xb, Bt, m0, n0, As, Bs, acc);
#pragma unroll
        for (int nt = 0; nt < 4; ++nt) {
            int n = n0 + wn + nt * 16 + c16;
            int h = n >> 6, d = n & 63;
            float bn = bias[n];
#pragma unroll
            for (int mt = 0; mt < 4; ++mt) {
                int m = m0 + wm + mt * 16 + g * 4;
                int b = m >> 12, s = m & (Sc - 1);
                size_t base = ((size_t)(b * Hc + h)) * Sc * Dc + (size_t)d * Sc + s;
                ushort4 pk;
                pk.x = to_bf16(acc[mt][nt][0] + bn);
                pk.y = to_bf16(acc[mt][nt][1] + bn);
                pk.z = to_bf16(acc[mt][nt][2] + bn);
                pk.w = to_bf16(acc[mt][nt][3] + bn);
                *(ushort4*)&vtg[base] = pk;
            }
        }
    } else {
        gemm128_core<1>(xb, Bt, m0, n0, As, Bs, acc);
        const float scale = z ? 1.0f : 0.125f;
        u16* outp = z ? kg : qg;
#pragma unroll
        for (int mt = 0; mt < 4; ++mt) {
            int m = m0 + wm + mt * 16 + c16;
            int b = m >> 12, s = m & (Sc - 1);
            size_t rowbase = (size_t)(b * Hc) * Sc * Dc + (size_t)s * Dc;
#pragma unroll
            for (int nt = 0; nt < 4; ++nt) {
                int nb = n0 + wn + nt * 16 + g * 4;
                int h = nb >> 6, d0 = nb & 63;
                float4 b4 = *(const float4*)&bias[nb];
                ushort4 pk;
                pk.x = to_bf16((acc[mt][nt][0] + b4.x) * scale);
                pk.y = to_bf16((acc[mt][nt][1] + b4.y) * scale);
                pk.z = to_bf16((acc[mt][nt][2] + b4.z) * scale);
                pk.w = to_bf16((acc[mt][nt][3] + b4.w) * scale);
                *(ushort4*)&outp[rowbase + (size_t)h * Sc * Dc + d0] = pk;
            }
        }
    }
}

// ---------------------------------------------------------------------------
// Output projection + residual (SWAP=1, R10 core, bf16 y out).
// 1D grid (384 blocks) with the same XCD-clustered decode (384 % 8 == 0):
// xcd owns m-tiles [xcd*8, xcd*8+8) x all 6 n — ctx slice 1.57MB + wdt
// 1.2MB L2-resident.
// ---------------------------------------------------------------------------
__global__ __launch_bounds__(256) void gemm_proj_mfma(
    const u16* __restrict__ ctxb, const u16* __restrict__ wdt,
    const float* __restrict__ bd, const float* __restrict__ x,
    u16* __restrict__ yb)
{
    __shared__ u16 As[16384], Bs[16384];

    const int wgid = blockIdx.x;
    const int xcd  = wgid & 7;
    const int j    = wgid >> 3;          // 0..47
    const int mt_  = xcd * 8 + (j & 7);
    const int nt_  = j >> 3;             // 0..5

    const int m0 = mt_ * 128, n0 = nt_ * 128;
    f32x4 acc[4][4];
#pragma unroll
    for (int i = 0; i < 4; ++i)
#pragma unroll
        for (int j2 = 0; j2 < 4; ++j2) acc[i][j2] = (f32x4){0.f, 0.f, 0.f, 0.f};

    gemm128_core<1>(ctxb, wdt, m0, n0, As, Bs, acc);

    const int lane = threadIdx.x & 63, wid = threadIdx.x >> 6;
    const int c16 = lane & 15, g = lane >> 4;
    const int wm = (wid >> 1) * 64, wn = (wid & 1) * 64;

#pragma unroll
    for (int mt = 0; mt < 4; ++mt) {
        int m = m0 + wm + mt * 16 + c16;
#pragma unroll
        for (int nt = 0; nt < 4; ++nt) {
            int nb = n0 + wn + nt * 16 + g * 4;
            float4 b4 = *(const float4*)&bd[nb];
            float4 x4 = *(const float4*)&x[(size_t)m * HIDc + nb];
            ushort4 pk;
            pk.x = to_bf16(acc[mt][nt][0] + b4.x + x4.x);
            pk.y = to_bf16(acc[mt][nt][1] + b4.y + x4.y);
            pk.z = to_bf16(acc[mt][nt][2] + b4.z + x4.z);
            pk.w = to_bf16(acc[mt][nt][3] + b4.w + x4.w);
            *(ushort4*)&yb[(size_t)m * HIDc + nb] = pk;
        }
    }
}

// ---------------------------------------------------------------------------
// MFMA banded attention v5 (R10 known-good): 128 queries/block, 8 waves,
// 384-row LDS-staged window, per-wave 18-tile band, pm overlays kwin,
// two-phase PV. (v6 direct-global K/V regressed 26->71us: load-on-demand
// MFMA operands are L2-latency-bound; bulk LDS prefetch wins.)
// ---------------------------------------------------------------------------
__global__ __launch_bounds__(512) void band_attn_mfma(
    const u16* __restrict__ qg, const u16* __restrict__ kg,
    const u16* __restrict__ vtg, const u16* __restrict__ zpad,
    u16* __restrict__ ctxb)
{
    extern __shared__ u16 sm[];
    u16* kwin = sm;            // [384][64] (49152B), swizzle seg^(row&7)
    u16* vt   = sm + 24576;    // [64][384], swizzle (sl&~7)|((sl^d)&7)
    u16* pm   = sm;            // [128][192-stride] overlay on kwin

    const int L = blockIdx.x;              // 0..767
    const int xcd = L & 7, tt = L >> 3;    // tt 0..95
    const int hb = xcd * 3 + (tt % 3);     // 0..23
    const int qc = tt / 3;                 // 0..31
    const int h = hb % Hc, b = hb / Hc;

    const int s0 = qc * QT3;
    const int tid = threadIdx.x;
    const int lane = tid & 63, w = tid >> 6;
    const int c16 = lane & 15, g = lane >> 4;
    const size_t hbase = ((size_t)(b * Hc + h)) * Sc * Dc;

    const u16* qp = &qg[hbase + (size_t)(s0 + w * 16 + c16) * Dc + g * 8];
    bf16x8 qa0 = *(const bf16x8*)qp;
    bf16x8 qa1 = *(const bf16x8*)(qp + 32);

#pragma unroll
    for (int i = 0; i < 6; ++i) {
        int c   = i * 8 + w;
        int row = c * 8 + (lane >> 3);
        int seg = (lane & 7) ^ (lane >> 3);
        int pos = s0 - Wc + row;
        const u16* src = (pos >= 0 && pos < Sc)
                       ? &kg[hbase + (size_t)pos * Dc + seg * 8] : zpad;
        load_lds16(src, (char*)kwin + c * 1024 + (lane & 63) * 16);
    }
#pragma unroll
    for (int i = 0; i < 6; ++i) {
        int c   = i * 8 + w;
        int idx = c * 64 + lane;
        int d   = idx / 48;
        int p   = idx - d * 48;
        int seg = (p & ~7) | ((p ^ d) & 7);
        int pos0 = s0 - Wc + seg * 8;
        const u16* src = (pos0 >= 0 && pos0 < Sc)
                       ? &vtg[hbase + (size_t)d * Sc + pos0] : zpad;
        load_lds16(src, (char*)vt + idx * 16);
    }

    VM_BAR(6);   // Q + kwin landed everywhere; vt's 6 loads still in flight

    const int tb  = w & ~1;
    const int off = (w & 1) * 16;
    f32x4 acc[NCT3];
#pragma unroll
    for (int ct = 0; ct < NCT3; ++ct) acc[ct] = (f32x4){0.f, 0.f, 0.f, 0.f};
    __builtin_amdgcn_s_setprio(1);
#pragma unroll
    for (int ct = 0; ct < NCT3; ++ct) {
        int row = (tb + ct) * 16 + c16;
        const u16* kb = kwin + row * 64;
        bf16x8 kb0 = *(const bf16x8*)(kb + (g       ^ (row & 7)) * 8);
        bf16x8 kb1 = *(const bf16x8*)(kb + ((g + 4) ^ (row & 7)) * 8);
        acc[ct] = __builtin_amdgcn_mfma_f32_16x16x32_bf16(qa0, kb0, acc[ct], 0, 0, 0);
        acc[ct] = __builtin_amdgcn_mfma_f32_16x16x32_bf16(qa1, kb1, acc[ct], 0, 0, 0);
    }
    __builtin_amdgcn_s_setprio(0);

    float mrow[4] = {-3e38f, -3e38f, -3e38f, -3e38f};
#pragma unroll
    for (int ct = 0; ct < NCT3; ++ct) {
#pragma unroll
        for (int r = 0; r < 4; ++r) {
            int ql  = g * 4 + r;
            int jl  = ct * 16 + c16 - off;
            int pos = s0 - Wc + (tb + ct) * 16 + c16;
            bool valid = (jl >= ql) && (jl <= ql + 2 * Wc) && (pos >= 0) && (pos < Sc);
            float v = valid ? acc[ct][r] : -3e38f;
            acc[ct][r] = v;
            mrow[r] = fmaxf(mrow[r], v);
        }
    }
#pragma unroll
    for (int r = 0; r < 4; ++r)
#pragma unroll
        for (int o2 = 1; o2 < 16; o2 <<= 1)
            mrow[r] = fmaxf(mrow[r], __shfl_xor(mrow[r], o2));

    float srow[4] = {0.f, 0.f, 0.f, 0.f};
#pragma unroll
    for (int ct = 0; ct < NCT3; ++ct)
#pragma unroll
        for (int r = 0; r < 4; ++r) {
            float e = __expf(acc[ct][r] - mrow[r]);
            acc[ct][r] = e;
            srow[r] += e;
        }
#pragma unroll
    for (int r = 0; r < 4; ++r)
#pragma unroll
        for (int o2 = 1; o2 < 16; o2 <<= 1)
            srow[r] += __shfl_xor(srow[r], o2);

    VM_BAR(0);   // all waves done reading kwin; vt fully landed

    float sq0 = __shfl(srow[0], (c16 >> 2) << 4);
    float sq1 = __shfl(srow[1], (c16 >> 2) << 4);
    float sq2 = __shfl(srow[2], (c16 >> 2) << 4);
    float sq3 = __shfl(srow[3], (c16 >> 2) << 4);
    int rr = c16 & 3;
    float sq = rr == 0 ? sq0 : rr == 1 ? sq1 : rr == 2 ? sq2 : sq3;
    float invq = 1.f / sq;

    const int qrow = w * 16 + c16;
    f32x4 o[4];
#pragma unroll
    for (int dt = 0; dt < 4; ++dt) o[dt] = (f32x4){0.f, 0.f, 0.f, 0.f};

    // ======== PV phase A: tiles 0..9 ========
#pragma unroll
    for (int ct = 0; ct < 10; ++ct)
#pragma unroll
        for (int r = 0; r < 4; ++r) {
            int q   = w * 16 + g * 4 + r;
            int col = ct * 16 + c16;
            int sl  = col >> 3;
            int ph  = (sl & ~7) | ((sl ^ q ^ (q >> 3)) & 7);
            pm[q * 192 + ph * 8 + (col & 7)] = to_bf16(acc[ct][r]);
        }
    __builtin_amdgcn_s_setprio(1);
#pragma unroll
    for (int ks = 0; ks < 5; ++ks) {
        int sl = ks * 4 + g;
        int ph = (sl & ~7) | ((sl ^ qrow ^ (qrow >> 3)) & 7);
        bf16x8 pa = *(const bf16x8*)(pm + qrow * 192 + ph * 8);
#pragma unroll
        for (int dt = 0; dt < 4; ++dt) {
            int d  = dt * 16 + c16;
            int vs = tb * 2 + ks * 4 + g;
            int pv = (vs & ~7) | ((vs ^ d) & 7);
            bf16x8 vb = *(const bf16x8*)(vt + d * 384 + pv * 8);
            o[dt] = __builtin_amdgcn_mfma_f32_16x16x32_bf16(vb, pa, o[dt], 0, 0, 0);
        }
    }
    __builtin_amdgcn_s_setprio(0);

    // ======== PV phase B: tiles 10..17 ========
#pragma unroll
    for (int ct = 10; ct < NCT3; ++ct)
#pragma unroll
        for (int r = 0; r < 4; ++r) {
            int q   = w * 16 + g * 4 + r;
            int col = ct * 16 + c16 - 160;
            int sl  = col >> 3;
            int ph  = (sl & ~7) | ((sl ^ q ^ (q >> 3)) & 7);
            pm[q * 192 + ph * 8 + (col & 7)] = to_bf16(acc[ct][r]);
        }
    __builtin_amdgcn_s_setprio(1);
#pragma unroll
    for (int ks = 0; ks < 4; ++ks) {
        int sl = ks * 4 + g;
        int ph = (sl & ~7) | ((sl ^ qrow ^ (qrow >> 3)) & 7);
        bf16x8 pa = *(const bf16x8*)(pm + qrow * 192 + ph * 8);
#pragma unroll
        for (int dt = 0; dt < 4; ++dt) {
            int d  = dt * 16 + c16;
            int vs = tb * 2 + 20 + ks * 4 + g;
            int pv = (vs & ~7) | ((vs ^ d) & 7);
            bf16x8 vb = *(const bf16x8*)(vt + d * 384 + pv * 8);
            o[dt] = __builtin_amdgcn_mfma_f32_16x16x32_bf16(vb, pa, o[dt], 0, 0, 0);
        }
    }
    __builtin_amdgcn_s_setprio(0);

    const size_t crow = ((size_t)(b * Sc + s0 + qrow)) * HIDc + h * Dc;
#pragma unroll
    for (int dt = 0; dt < 4; ++dt) {
        ushort4 pk;
        pk.x = to_bf16(o[dt][0] * invq);
        pk.y = to_bf16(o[dt][1] * invq);
        pk.z = to_bf16(o[dt][2] * invq);
        pk.w = to_bf16(o[dt][3] * invq);
        *(ushort4*)&ctxb[crow + dt * 16 + g * 4] = pk;
    }
}

// ---------------------------------------------------------------------------
// LayerNorm v2: y is bf16. 8192 blocks x 192 threads; one ushort4/thread,
// fp32 math, fp32 out.
// ---------------------------------------------------------------------------
__global__ __launch_bounds__(192) void ln_kernel(
    const u16* __restrict__ yb,
    const float* __restrict__ gamma, const float* __restrict__ beta,
    float* __restrict__ out)
{
    const int m = blockIdx.x;
    const int t = threadIdx.x;
    const int lane = t & 63, wid = t >> 6;

    ushort4 v4 = *(const ushort4*)&yb[(size_t)m * HIDc + t * 4];
    float v0 = from_bf16(v4.x), v1 = from_bf16(v4.y);
    float v2 = from_bf16(v4.z), v3 = from_bf16(v4.w);

    __shared__ float red[3];
    float s = v0 + v1 + v2 + v3;
#pragma unroll
    for (int o = 1; o < 64; o <<= 1) s += __shfl_xor(s, o);
    if (lane == 0) red[wid] = s;
    __syncthreads();
    const float mu = (red[0] + red[1] + red[2]) * (1.f / HIDc);
    v0 -= mu; v1 -= mu; v2 -= mu; v3 -= mu;
    float s2 = v0 * v0 + v1 * v1 + v2 * v2 + v3 * v3;
#pragma unroll
    for (int o = 1; o < 64; o <<= 1) s2 += __shfl_xor(s2, o);
    __syncthreads();
    if (lane == 0) red[wid] = s2;
    __syncthreads();
    const float var = (red[0] + red[1] + red[2]) * (1.f / HIDc);
    const float rstd = rsqrtf(var + 1e-12f);

    float4 g4 = *(const float4*)&gamma[t * 4];
    float4 b4 = *(const float4*)&beta[t * 4];
    float4 o4;
    o4.x = v0 * rstd * g4.x + b4.x;
    o4.y = v1 * rstd * g4.y + b4.y;
    o4.z = v2 * rstd * g4.z + b4.z;
    o4.w = v3 * rstd * g4.w + b4.w;
    *(float4*)&out[(size_t)m * HIDc + t * 4] = o4;
}

// ---------------------------------------------------------------------------
extern "C" void kernel_launch(void* const* d_in, const int* in_sizes, int n_in,
                              void* d_out, int out_size, void* d_ws, size_t ws_size,
                              hipStream_t stream)
{
    const float* x     = (const float*)d_in[0];
    const float* Wq    = (const float*)d_in[1];
    const float* bq    = (const float*)d_in[2];
    const float* Wk    = (const float*)d_in[3];
    const float* bk    = (const float*)d_in[4];
    const float* Wv    = (const float*)d_in[5];
    const float* bv    = (const float*)d_in[6];
    const float* Wd    = (const float*)d_in[7];
    const float* bd    = (const float*)d_in[8];
    const float* gamma = (const float*)d_in[9];
    const float* beta  = (const float*)d_in[10];
    float* out = (float*)d_out;

    constexpr size_t CHUNK = (size_t)Mc * HIDc;      // 6,291,456
    constexpr size_t WSZ   = (size_t)HIDc * HIDc;    //   589,824
    u16* xb   = (u16*)d_ws;
    u16* wqt  = xb + CHUNK;
    u16* wkt  = wqt + WSZ;
    u16* wvt  = wkt + WSZ;
    u16* wdt  = wvt + WSZ;
    u16* qg   = wdt + WSZ;
    u16* kg   = qg + CHUNK;
    u16* vtg  = kg + CHUNK;
    u16* ctxb = vtg + CHUNK;
    u16* yb   = ctxb + CHUNK;           // bf16 y (pre-LN)
    u16* zpad = yb + CHUNK;             // 2KB zero guard (filled by prep_all)

    // 0) fused precision prep (x->bf16, W->Wt bf16, zpad)
    prep_all<<<6144 + 2304, 256, 0, stream>>>(
        x, xb, zpad, Wq, Wk, Wv, Wd, wqt, wkt, wvt, wdt);

    // 1) merged QKV projections (R10 core + XCD-clustered 1D grid)
    gemm_qkv_mfma<<<1152, 256, 0, stream>>>(
        xb, wqt, wkt, wvt, bq, bk, bv, qg, kg, vtg);

    // 2) banded attention v5 (staged window, 96KB LDS)
    band_attn_mfma<<<dim3(Sc / QT3 * Hc * Bc), 512, 98304, stream>>>(
        qg, kg, vtg, zpad, ctxb);

    // 3) output projection + residual (R10 core + XCD swizzle, bf16 y out)
    gemm_proj_mfma<<<384, 256, 0, stream>>>(
        ctxb, wdt, bd, x, yb);

    // 4) LayerNorm (bf16 in, fp32 out)
    ln_kernel<<<Mc, 192, 0, stream>>>(yb, gamma, beta, out);
}

// Round 18
// 120.262 us; speedup vs baseline: 1.3746x; 1.0013x over previous
//
#include <hip/hip_runtime.h>
#include <math.h>

typedef unsigned short u16;
typedef __bf16 bf16x8 __attribute__((ext_vector_type(8)));
typedef float f32x4 __attribute__((ext_vector_type(4)));

// Problem constants
constexpr int Bc   = 2;
constexpr int Sc   = 4096;
constexpr int HIDc = 768;
constexpr int Hc   = 12;
constexpr int Dc   = 64;
constexpr int Wc   = 128;
constexpr int Mc   = Bc * Sc;

// attention tiling (v5): 128 queries/block, 8 waves, per-wave 18-tile band
constexpr int QT3  = 128;
constexpr int NCT3 = 18;

#define VM_BAR(N) asm volatile("s_waitcnt vmcnt(" #N ")\n\ts_barrier" ::: "memory")
#define BAR()     asm volatile("s_barrier" ::: "memory")

static __device__ __forceinline__ void load_lds16(const void* g, void* l) {
    __builtin_amdgcn_global_load_lds(
        (const __attribute__((address_space(1))) void*)g,
        (__attribute__((address_space(3))) void*)l, 16, 0, 0);
}
static __device__ __forceinline__ u16 to_bf16(float f) {
    return __builtin_bit_cast(u16, (__bf16)f);
}
static __device__ __forceinline__ float from_bf16(u16 u) {
    return (float)__builtin_bit_cast(__bf16, u);
}

// ---------------------------------------------------------------------------
// Fused prep: blocks [0,6144): x fp32 -> bf16 (+ zpad fill in block 0);
// blocks [6144,8448): transpose W [K][N] fp32 -> Wt [N][K] bf16.
// ---------------------------------------------------------------------------
__global__ __launch_bounds__(256) void prep_all(
    const float* __restrict__ x, u16* __restrict__ xb, u16* __restrict__ zpad,
    const float* __restrict__ Wq, const float* __restrict__ Wk,
    const float* __restrict__ Wv, const float* __restrict__ Wd,
    u16* __restrict__ wqt, u16* __restrict__ wkt,
    u16* __restrict__ wvt, u16* __restrict__ wdt)
{
    const int bid = blockIdx.x;
    if (bid < 6144) {
        int i = bid * 256 + threadIdx.x;
        float4 v = ((const float4*)x)[i];
        ushort4 o;
        o.x = to_bf16(v.x); o.y = to_bf16(v.y);
        o.z = to_bf16(v.z); o.w = to_bf16(v.w);
        ((ushort4*)xb)[i] = o;
        if (bid == 0 && threadIdx.x < 128)
            ((int4*)zpad)[threadIdx.x] = make_int4(0, 0, 0, 0);  // 2KB zeros
    } else {
        int r = bid - 6144;                 // 0..2303
        int z = r / 576, xy = r - z * 576;  // 576 = 24*24 tiles per matrix
        const float* W = z == 0 ? Wq : z == 1 ? Wk : z == 2 ? Wv : Wd;
        u16* T         = z == 0 ? wqt : z == 1 ? wkt : z == 2 ? wvt : wdt;
        __shared__ float t[32][33];
        const int bx = (xy % 24) * 32, by = (xy / 24) * 32;
        const int tx = threadIdx.x & 31, ty = threadIdx.x >> 5;
#pragma unroll
        for (int i = 0; i < 32; i += 8)
            t[ty + i][tx] = W[(size_t)(by + ty + i) * HIDc + bx + tx];
        __syncthreads();
#pragma unroll
        for (int i = 0; i < 32; i += 8)
            T[(size_t)(bx + ty + i) * HIDc + by + tx] = to_bf16(t[tx][ty + i]);
    }
}

// ---------------------------------------------------------------------------
// BK=64 tile pair stager (R10 known-good): 128 rows x 64 k each for A, B^T.
// Row = 128B = 8 x 16B slots; swizzle slot8 = phys ^ (row&7).
// 8 global_load_lds per wave (4 A + 4 B) -> vmcnt unit = 8.
// ---------------------------------------------------------------------------
__device__ __forceinline__ void stage64(const u16* __restrict__ A,
                                        const u16* __restrict__ Bt,
                                        int m0, int n0, int k0,
                                        u16* As, u16* Bs, int soff)
{
#pragma unroll
    for (int i = 0; i < 4; ++i) {
        int off  = soff + i * 1024;
        int row  = off >> 7;
        int slot = (off >> 4) & 7;
        int seg  = slot ^ (row & 7);
        load_lds16(A  + (size_t)(m0 + row) * HIDc + k0 + seg * 8, (char*)As + off);
        load_lds16(Bt + (size_t)(n0 + row) * HIDc + k0 + seg * 8, (char*)Bs + off);
    }
}

// ---------------------------------------------------------------------------
// 128x128 B^T MFMA GEMM core, K=768, BK=64, double-buffered (64KB LDS) with
// COUNTED vmcnt: per iter {STAGE(t+1); vmcnt(8)+bar; ds_read+MFMA(t); bar}.
// Terminal config: measured 527 TF at this shape — above the m97-family
// reference curve (~320 TF @ N=2048-equiv). 7 structural variants regressed.
// SWAP=0: acc row=m, col=n.  SWAP=1: operands swapped -> row=n, col=m.
// ---------------------------------------------------------------------------
template <int SWAP>
__device__ __forceinline__ void gemm128_core(
    const u16* __restrict__ A, const u16* __restrict__ Bt,
    int m0, int n0, u16* As, u16* Bs, f32x4 (&acc)[4][4])
{
    const int lane = threadIdx.x & 63, wid = threadIdx.x >> 6;
    const int c16 = lane & 15, g = lane >> 4;
    const int wm = (wid >> 1) * 64, wn = (wid & 1) * 64;
    const int soff = wid * 4096 + lane * 16;

    stage64(A, Bt, m0, n0, 0, As, Bs, soff);
    int cur = 0;
    for (int t = 0; t < 12; ++t) {
        if (t < 11) {
            stage64(A, Bt, m0, n0, (t + 1) * 64,
                    As + (cur ^ 1) * 8192, Bs + (cur ^ 1) * 8192, soff);
            VM_BAR(8);          // stage(t) landed; stage(t+1) in flight
        } else {
            VM_BAR(0);
        }
        const u16* Ab = As + cur * 8192;
        const u16* Bb = Bs + cur * 8192;
#pragma unroll
        for (int kk = 0; kk < 2; ++kk) {
            bf16x8 af[4], bfr[4];
#pragma unroll
            for (int tt = 0; tt < 4; ++tt) {
                int ar = wm + tt * 16 + c16;
                int a8 = (kk * 4 + g) ^ (ar & 7);
                af[tt] = *(const bf16x8*)(Ab + ar * 64 + a8 * 8);
                int br = wn + tt * 16 + c16;
                int b8 = (kk * 4 + g) ^ (br & 7);
                bfr[tt] = *(const bf16x8*)(Bb + br * 64 + b8 * 8);
            }
            __builtin_amdgcn_s_setprio(1);
#pragma unroll
            for (int mt = 0; mt < 4; ++mt)
#pragma unroll
                for (int nt = 0; nt < 4; ++nt)
                    acc[mt][nt] = SWAP
                        ? __builtin_amdgcn_mfma_f32_16x16x32_bf16(
                              bfr[nt], af[mt], acc[mt][nt], 0, 0, 0)
                        : __builtin_amdgcn_mfma_f32_16x16x32_bf16(
                              af[mt], bfr[nt], acc[mt][nt], 0, 0, 0);
            __builtin_amdgcn_s_setprio(0);
        }
        BAR();
        cur ^= 1;
    }
}

// ---------------------------------------------------------------------------
// Merged QKV projection, 1D grid with XCD-aware decode (1152 % 8 == 0):
// xcd = wgid&7 owns m-tiles [xcd*8, xcd*8+8) x all 18 (n,z). FETCH -17%.
// z=0/1 (Q,K): SWAP=1 -> ushort4 store into [B,H,S,D] (Q scaled 1/8).
// z=2   (V) : SWAP=0 -> ushort4 store into transposed [B,H,D,S].
// ---------------------------------------------------------------------------
__global__ __launch_bounds__(256) void gemm_qkv_mfma(
    const u16* __restrict__ xb,
    const u16* __restrict__ wqt, const u16* __restrict__ wkt,
    const u16* __restrict__ wvt,
    const float* __restrict__ bq, const float* __restrict__ bk,
    const float* __restrict__ bv,
    u16* __restrict__ qg, u16* __restrict__ kg, u16* __restrict__ vtg)
{
    __shared__ u16 As[16384], Bs[16384];

    const int wgid = blockIdx.x;
    const int xcd  = wgid & 7;
    const int j    = wgid >> 3;          // 0..143
    const int mt_  = xcd * 8 + (j & 7);  // m-tile 0..63
    const int rest = j >> 3;             // 0..17
    const int nt_  = rest % 6;
    const int z    = rest / 6;

    const u16* Bt     = z == 0 ? wqt : z == 1 ? wkt : wvt;
    const float* bias = z == 0 ? bq : z == 1 ? bk : bv;

    const int m0 = mt_ * 128, n0 = nt_ * 128;
    f32x4 acc[4][4];
#pragma unroll
    for (int i = 0; i < 4; ++i)
#pragma unroll
        for (int j2 = 0; j2 < 4; ++j2) acc[i][j2] = (f32x4){0.f, 0.f, 0.f, 0.f};

    const int lane = threadIdx.x & 63, wid = threadIdx.x >> 6;
    const int c16 = lane & 15, g = lane >> 4;
    const int wm = (wid >> 1) * 64, wn = (wid & 1) * 64;

    if (z == 2) {
        gemm128_core<0>(xb, Bt, m0, n0, As, Bs, acc);
#pragma unroll
        for (int nt = 0; nt < 4; ++nt) {
            int n = n0 + wn + nt * 16 + c16;
            int h = n >> 6, d = n & 63;
            float bn = bias[n];
#pragma unroll
            for (int mt = 0; mt < 4; ++mt) {
                int m = m0 + wm + mt * 16 + g * 4;
                int b = m >> 12, s = m & (Sc - 1);
                size_t base = ((size_t)(b * Hc + h)) * Sc * Dc + (size_t)d * Sc + s;
                ushort4 pk;
                pk.x = to_bf16(acc[mt][nt][0] + bn);
                pk.y = to_bf16(acc[mt][nt][1] + bn);
                pk.z = to_bf16(acc[mt][nt][2] + bn);
                pk.w = to_bf16(acc[mt][nt][3] + bn);
                *(ushort4*)&vtg[base] = pk;
            }
        }
    } else {
        gemm128_core<1>(xb, Bt, m0, n0, As, Bs, acc);
        const float scale = z ? 1.0f : 0.125f;
        u16* outp = z ? kg : qg;
#pragma unroll
        for (int mt = 0; mt < 4; ++mt) {
            int m = m0 + wm + mt * 16 + c16;
            int b = m >> 12, s = m & (Sc - 1);
            size_t rowbase = (size_t)(b * Hc) * Sc * Dc + (size_t)s * Dc;
#pragma unroll
            for (int nt = 0; nt < 4; ++nt) {
                int nb = n0 + wn + nt * 16 + g * 4;
                int h = nb >> 6, d0 = nb & 63;
                float4 b4 = *(const float4*)&bias[nb];
                ushort4 pk;
                pk.x = to_bf16((acc[mt][nt][0] + b4.x) * scale);
                pk.y = to_bf16((acc[mt][nt][1] + b4.y) * scale);
                pk.z = to_bf16((acc[mt][nt][2] + b4.z) * scale);
                pk.w = to_bf16((acc[mt][nt][3] + b4.w) * scale);
                *(ushort4*)&outp[rowbase + (size_t)h * Sc * Dc + d0] = pk;
            }
        }
    }
}

// ---------------------------------------------------------------------------
// Output projection + residual (SWAP=1, XCD swizzle, bf16 y out).
// NEW: residual read from xb (bf16, 12.5MB) instead of x (fp32, 25MB) —
// x is already faithfully represented in xb; add stays fp32.
// ---------------------------------------------------------------------------
__global__ __launch_bounds__(256) void gemm_proj_mfma(
    const u16* __restrict__ ctxb, const u16* __restrict__ wdt,
    const float* __restrict__ bd, const u16* __restrict__ xb,
    u16* __restrict__ yb)
{
    __shared__ u16 As[16384], Bs[16384];

    const int wgid = blockIdx.x;
    const int xcd  = wgid & 7;
    const int j    = wgid >> 3;          // 0..47
    const int mt_  = xcd * 8 + (j & 7);
    const int nt_  = j >> 3;             // 0..5

    const int m0 = mt_ * 128, n0 = nt_ * 128;
    f32x4 acc[4][4];
#pragma unroll
    for (int i = 0; i < 4; ++i)
#pragma unroll
        for (int j2 = 0; j2 < 4; ++j2) acc[i][j2] = (f32x4){0.f, 0.f, 0.f, 0.f};

    gemm128_core<1>(ctxb, wdt, m0, n0, As, Bs, acc);

    const int lane = threadIdx.x & 63, wid = threadIdx.x >> 6;
    const int c16 = lane & 15, g = lane >> 4;
    const int wm = (wid >> 1) * 64, wn = (wid & 1) * 64;

#pragma unroll
    for (int mt = 0; mt < 4; ++mt) {
        int m = m0 + wm + mt * 16 + c16;
#pragma unroll
        for (int nt = 0; nt < 4; ++nt) {
            int nb = n0 + wn + nt * 16 + g * 4;
            float4 b4 = *(const float4*)&bd[nb];
            ushort4 x4 = *(const ushort4*)&xb[(size_t)m * HIDc + nb];
            ushort4 pk;
            pk.x = to_bf16(acc[mt][nt][0] + b4.x + from_bf16(x4.x));
            pk.y = to_bf16(acc[mt][nt][1] + b4.y + from_bf16(x4.y));
            pk.z = to_bf16(acc[mt][nt][2] + b4.z + from_bf16(x4.z));
            pk.w = to_bf16(acc[mt][nt][3] + b4.w + from_bf16(x4.w));
            *(ushort4*)&yb[(size_t)m * HIDc + nb] = pk;
        }
    }
}

// ---------------------------------------------------------------------------
// MFMA banded attention v5 (known-good): 128 queries/block, 8 waves,
// 384-row LDS-staged window, per-wave 18-tile band, pm overlays kwin,
// two-phase PV. (v6 direct-global K/V regressed 26->71us: load-on-demand
// MFMA operands are L2-latency-bound; bulk LDS prefetch wins.)
// ---------------------------------------------------------------------------
__global__ __launch_bounds__(512) void band_attn_mfma(
    const u16* __restrict__ qg, const u16* __restrict__ kg,
    const u16* __restrict__ vtg, const u16* __restrict__ zpad,
    u16* __restrict__ ctxb)
{
    extern __shared__ u16 sm[];
    u16* kwin = sm;            // [384][64] (49152B), swizzle seg^(row&7)
    u16* vt   = sm + 24576;    // [64][384], swizzle (sl&~7)|((sl^d)&7)
    u16* pm   = sm;            // [128][192-stride] overlay on kwin

    const int L = blockIdx.x;              // 0..767
    const int xcd = L & 7, tt = L >> 3;    // tt 0..95
    const int hb = xcd * 3 + (tt % 3);     // 0..23
    const int qc = tt / 3;                 // 0..31
    const int h = hb % Hc, b = hb / Hc;

    const int s0 = qc * QT3;
    const int tid = threadIdx.x;
    const int lane = tid & 63, w = tid >> 6;
    const int c16 = lane & 15, g = lane >> 4;
    const size_t hbase = ((size_t)(b * Hc + h)) * Sc * Dc;

    const u16* qp = &qg[hbase + (size_t)(s0 + w * 16 + c16) * Dc + g * 8];
    bf16x8 qa0 = *(const bf16x8*)qp;
    bf16x8 qa1 = *(const bf16x8*)(qp + 32);

#pragma unroll
    for (int i = 0; i < 6; ++i) {
        int c   = i * 8 + w;
        int row = c * 8 + (lane >> 3);
        int seg = (lane & 7) ^ (lane >> 3);
        int pos = s0 - Wc + row;
        const u16* src = (pos >= 0 && pos < Sc)
                       ? &kg[hbase + (size_t)pos * Dc + seg * 8] : zpad;
        load_lds16(src, (char*)kwin + c * 1024 + (lane & 63) * 16);
    }
#pragma unroll
    for (int i = 0; i < 6; ++i) {
        int c   = i * 8 + w;
        int idx = c * 64 + lane;
        int d   = idx / 48;
        int p   = idx - d * 48;
        int seg = (p & ~7) | ((p ^ d) & 7);
        int pos0 = s0 - Wc + seg * 8;
        const u16* src = (pos0 >= 0 && pos0 < Sc)
                       ? &vtg[hbase + (size_t)d * Sc + pos0] : zpad;
        load_lds16(src, (char*)vt + idx * 16);
    }

    VM_BAR(6);   // Q + kwin landed everywhere; vt's 6 loads still in flight

    const int tb  = w & ~1;
    const int off = (w & 1) * 16;
    f32x4 acc[NCT3];
#pragma unroll
    for (int ct = 0; ct < NCT3; ++ct) acc[ct] = (f32x4){0.f, 0.f, 0.f, 0.f};
    __builtin_amdgcn_s_setprio(1);
#pragma unroll
    for (int ct = 0; ct < NCT3; ++ct) {
        int row = (tb + ct) * 16 + c16;
        const u16* kb = kwin + row * 64;
        bf16x8 kb0 = *(const bf16x8*)(kb + (g       ^ (row & 7)) * 8);
        bf16x8 kb1 = *(const bf16x8*)(kb + ((g + 4) ^ (row & 7)) * 8);
        acc[ct] = __builtin_amdgcn_mfma_f32_16x16x32_bf16(qa0, kb0, acc[ct], 0, 0, 0);
        acc[ct] = __builtin_amdgcn_mfma_f32_16x16x32_bf16(qa1, kb1, acc[ct], 0, 0, 0);
    }
    __builtin_amdgcn_s_setprio(0);

    float mrow[4] = {-3e38f, -3e38f, -3e38f, -3e38f};
#pragma unroll
    for (int ct = 0; ct < NCT3; ++ct) {
#pragma unroll
        for (int r = 0; r < 4; ++r) {
            int ql  = g * 4 + r;
            int jl  = ct * 16 + c16 - off;
            int pos = s0 - Wc + (tb + ct) * 16 + c16;
            bool valid = (jl >= ql) && (jl <= ql + 2 * Wc) && (pos >= 0) && (pos < Sc);
            float v = valid ? acc[ct][r] : -3e38f;
            acc[ct][r] = v;
            mrow[r] = fmaxf(mrow[r], v);
        }
    }
#pragma unroll
    for (int r = 0; r < 4; ++r)
#pragma unroll
        for (int o2 = 1; o2 < 16; o2 <<= 1)
            mrow[r] = fmaxf(mrow[r], __shfl_xor(mrow[r], o2));

    float srow[4] = {0.f, 0.f, 0.f, 0.f};
#pragma unroll
    for (int ct = 0; ct < NCT3; ++ct)
#pragma unroll
        for (int r = 0; r < 4; ++r) {
            float e = __expf(acc[ct][r] - mrow[r]);
            acc[ct][r] = e;
            srow[r] += e;
        }
#pragma unroll
    for (int r = 0; r < 4; ++r)
#pragma unroll
        for (int o2 = 1; o2 < 16; o2 <<= 1)
            srow[r] += __shfl_xor(srow[r], o2);

    VM_BAR(0);   // all waves done reading kwin; vt fully landed

    float sq0 = __shfl(srow[0], (c16 >> 2) << 4);
    float sq1 = __shfl(srow[1], (c16 >> 2) << 4);
    float sq2 = __shfl(srow[2], (c16 >> 2) << 4);
    float sq3 = __shfl(srow[3], (c16 >> 2) << 4);
    int rr = c16 & 3;
    float sq = rr == 0 ? sq0 : rr == 1 ? sq1 : rr == 2 ? sq2 : sq3;
    float invq = 1.f / sq;

    const int qrow = w * 16 + c16;
    f32x4 o[4];
#pragma unroll
    for (int dt = 0; dt < 4; ++dt) o[dt] = (f32x4){0.f, 0.f, 0.f, 0.f};

    // ======== PV phase A: tiles 0..9 ========
#pragma unroll
    for (int ct = 0; ct < 10; ++ct)
#pragma unroll
        for (int r = 0; r < 4; ++r) {
            int q   = w * 16 + g * 4 + r;
            int col = ct * 16 + c16;
            int sl  = col >> 3;
            int ph  = (sl & ~7) | ((sl ^ q ^ (q >> 3)) & 7);
            pm[q * 192 + ph * 8 + (col & 7)] = to_bf16(acc[ct][r]);
        }
    __builtin_amdgcn_s_setprio(1);
#pragma unroll
    for (int ks = 0; ks < 5; ++ks) {
        int sl = ks * 4 + g;
        int ph = (sl & ~7) | ((sl ^ qrow ^ (qrow >> 3)) & 7);
        bf16x8 pa = *(const bf16x8*)(pm + qrow * 192 + ph * 8);
#pragma unroll
        for (int dt = 0; dt < 4; ++dt) {
            int d  = dt * 16 + c16;
            int vs = tb * 2 + ks * 4 + g;
            int pv = (vs & ~7) | ((vs ^ d) & 7);
            bf16x8 vb = *(const bf16x8*)(vt + d * 384 + pv * 8);
            o[dt] = __builtin_amdgcn_mfma_f32_16x16x32_bf16(vb, pa, o[dt], 0, 0, 0);
        }
    }
    __builtin_amdgcn_s_setprio(0);

    // ======== PV phase B: tiles 10..17 ========
#pragma unroll
    for (int ct = 10; ct < NCT3; ++ct)
#pragma unroll
        for (int r = 0; r < 4; ++r) {
            int q   = w * 16 + g * 4 + r;
            int col = ct * 16 + c16 - 160;
            int sl  = col >> 3;
            int ph  = (sl & ~7) | ((sl ^ q ^ (q >> 3)) & 7);
            pm[q * 192 + ph * 8 + (col & 7)] = to_bf16(acc[ct][r]);
        }
    __builtin_amdgcn_s_setprio(1);
#pragma unroll
    for (int ks = 0; ks < 4; ++ks) {
        int sl = ks * 4 + g;
        int ph = (sl & ~7) | ((sl ^ qrow ^ (qrow >> 3)) & 7);
        bf16x8 pa = *(const bf16x8*)(pm + qrow * 192 + ph * 8);
#pragma unroll
        for (int dt = 0; dt < 4; ++dt) {
            int d  = dt * 16 + c16;
            int vs = tb * 2 + 20 + ks * 4 + g;
            int pv = (vs & ~7) | ((vs ^ d) & 7);
            bf16x8 vb = *(const bf16x8*)(vt + d * 384 + pv * 8);
            o[dt] = __builtin_amdgcn_mfma_f32_16x16x32_bf16(vb, pa, o[dt], 0, 0, 0);
        }
    }
    __builtin_amdgcn_s_setprio(0);

    const size_t crow = ((size_t)(b * Sc + s0 + qrow)) * HIDc + h * Dc;
#pragma unroll
    for (int dt = 0; dt < 4; ++dt) {
        ushort4 pk;
        pk.x = to_bf16(o[dt][0] * invq);
        pk.y = to_bf16(o[dt][1] * invq);
        pk.z = to_bf16(o[dt][2] * invq);
        pk.w = to_bf16(o[dt][3] * invq);
        *(ushort4*)&ctxb[crow + dt * 16 + g * 4] = pk;
    }
}

// ---------------------------------------------------------------------------
// LayerNorm v2: y is bf16. 8192 blocks x 192 threads; one ushort4/thread,
// fp32 math, fp32 out.
// ---------------------------------------------------------------------------
__global__ __launch_bounds__(192) void ln_kernel(
    const u16* __restrict__ yb,
    const float* __restrict__ gamma, const float* __restrict__ beta,
    float* __restrict__ out)
{
    const int m = blockIdx.x;
    const int t = threadIdx.x;
    const int lane = t & 63, wid = t >> 6;

    ushort4 v4 = *(const ushort4*)&yb[(size_t)m * HIDc + t * 4];
    float v0 = from_bf16(v4.x), v1 = from_bf16(v4.y);
    float v2 = from_bf16(v4.z), v3 = from_bf16(v4.w);

    __shared__ float red[3];
    float s = v0 + v1 + v2 + v3;
#pragma unroll
    for (int o = 1; o < 64; o <<= 1) s += __shfl_xor(s, o);
    if (lane == 0) red[wid] = s;
    __syncthreads();
    const float mu = (red[0] + red[1] + red[2]) * (1.f / HIDc);
    v0 -= mu; v1 -= mu; v2 -= mu; v3 -= mu;
    float s2 = v0 * v0 + v1 * v1 + v2 * v2 + v3 * v3;
#pragma unroll
    for (int o = 1; o < 64; o <<= 1) s2 += __shfl_xor(s2, o);
    __syncthreads();
    if (lane == 0) red[wid] = s2;
    __syncthreads();
    const float var = (red[0] + red[1] + red[2]) * (1.f / HIDc);
    const float rstd = rsqrtf(var + 1e-12f);

    float4 g4 = *(const float4*)&gamma[t * 4];
    float4 b4 = *(const float4*)&beta[t * 4];
    float4 o4;
    o4.x = v0 * rstd * g4.x + b4.x;
    o4.y = v1 * rstd * g4.y + b4.y;
    o4.z = v2 * rstd * g4.z + b4.z;
    o4.w = v3 * rstd * g4.w + b4.w;
    *(float4*)&out[(size_t)m * HIDc + t * 4] = o4;
}

// ---------------------------------------------------------------------------
extern "C" void kernel_launch(void* const* d_in, const int* in_sizes, int n_in,
                              void* d_out, int out_size, void* d_ws, size_t ws_size,
                              hipStream_t stream)
{
    const float* x     = (const float*)d_in[0];
    const float* Wq    = (const float*)d_in[1];
    const float* bq    = (const float*)d_in[2];
    const float* Wk    = (const float*)d_in[3];
    const float* bk    = (const float*)d_in[4];
    const float* Wv    = (const float*)d_in[5];
    const float* bv    = (const float*)d_in[6];
    const float* Wd    = (const float*)d_in[7];
    const float* bd    = (const float*)d_in[8];
    const float* gamma = (const float*)d_in[9];
    const float* beta  = (const float*)d_in[10];
    float* out = (float*)d_out;

    constexpr size_t CHUNK = (size_t)Mc * HIDc;      // 6,291,456
    constexpr size_t WSZ   = (size_t)HIDc * HIDc;    //   589,824
    u16* xb   = (u16*)d_ws;
    u16* wqt  = xb + CHUNK;
    u16* wkt  = wqt + WSZ;
    u16* wvt  = wkt + WSZ;
    u16* wdt  = wvt + WSZ;
    u16* qg   = wdt + WSZ;
    u16* kg   = qg + CHUNK;
    u16* vtg  = kg + CHUNK;
    u16* ctxb = vtg + CHUNK;
    u16* yb   = ctxb + CHUNK;           // bf16 y (pre-LN)
    u16* zpad = yb + CHUNK;             // 2KB zero guard (filled by prep_all)

    // 0) fused precision prep (x->bf16, W->Wt bf16, zpad)
    prep_all<<<6144 + 2304, 256, 0, stream>>>(
        x, xb, zpad, Wq, Wk, Wv, Wd, wqt, wkt, wvt, wdt);

    // 1) merged QKV projections (R10 core + XCD-clustered 1D grid)
    gemm_qkv_mfma<<<1152, 256, 0, stream>>>(
        xb, wqt, wkt, wvt, bq, bk, bv, qg, kg, vtg);

    // 2) banded attention v5 (staged window, 96KB LDS)
    band_attn_mfma<<<dim3(Sc / QT3 * Hc * Bc), 512, 98304, stream>>>(
        qg, kg, vtg, zpad, ctxb);

    // 3) output projection + residual (bf16 residual read, bf16 y out)
    gemm_proj_mfma<<<384, 256, 0, stream>>>(
        ctxb, wdt, bd, xb, yb);

    // 4) LayerNorm (bf16 in, fp32 out)
    ln_kernel<<<Mc, 192, 0, stream>>>(yb, gamma, beta, out);
}